// Round 2
// baseline (2141.937 us; speedup 1.0000x reference)
//
#include <hip/hip_runtime.h>

#define NN 50000
#define NE 800000

// ---------------- init: deg=1 (self-loop), zero accumulators ----------------
__global__ void k_init(float* __restrict__ deg, float* __restrict__ agg1,
                       float* __restrict__ agg2) {
    int tid = blockIdx.x * blockDim.x + threadIdx.x;
    int stride = gridDim.x * blockDim.x;
    for (int i = tid; i < NN; i += stride) deg[i] = 1.0f;
    for (int i = tid; i < NN * 128; i += stride) agg1[i] = 0.0f;
    for (int i = tid; i < NN * 64; i += stride) agg2[i] = 0.0f;
}

// ---------------- degree count (in-degree at dst) ----------------
__global__ void k_deg(const int* __restrict__ dst, float* __restrict__ deg) {
    int e = blockIdx.x * blockDim.x + threadIdx.x;
    if (e < NE) atomicAdd(&deg[dst[e]], 1.0f);
}

__global__ void k_rsqrt(float* __restrict__ deg) {
    int i = blockIdx.x * blockDim.x + threadIdx.x;
    if (i < NN) deg[i] = rsqrtf(deg[i]);  // deg >= 1 always (self-loop)
}

// ---------------- edge prep: norm[e] = dinv[src]*dinv[dst] ----------------
__global__ void k_edgeprep(const int* __restrict__ src, const int* __restrict__ dst,
                           const float* __restrict__ dinv, float* __restrict__ norm) {
    int e = blockIdx.x * blockDim.x + threadIdx.x;
    if (e >= NE) return;
    norm[e] = dinv[src[e]] * dinv[dst[e]];
}

// ---------------- f32 GEMM: H[N,M] = X[N,128] @ W[128,M] ----------------
// block = M threads (one col each), 8 rows per block, X rows staged in LDS.
template <int M>
__global__ void k_gemm(const float* __restrict__ X, const float* __restrict__ W,
                       float* __restrict__ H) {
    __shared__ float xs[8][128];
    const int c = threadIdx.x;  // 0..M-1
    const int r0 = blockIdx.x * 8;
    for (int idx = threadIdx.x; idx < 8 * 128; idx += M) {
        int r = idx >> 7, k = idx & 127;
        xs[r][k] = X[(long long)(r0 + r) * 128 + k];
    }
    __syncthreads();
    float acc[8];
#pragma unroll
    for (int r = 0; r < 8; ++r) acc[r] = 0.0f;
#pragma unroll 4
    for (int k = 0; k < 128; ++k) {
        float wv = W[k * M + c];
#pragma unroll
        for (int r = 0; r < 8; ++r) acc[r] = fmaf(xs[r][k], wv, acc[r]);
    }
#pragma unroll
    for (int r = 0; r < 8; ++r)
        H[(long long)(r0 + r) * M + c] = acc[r];
}

// ---------------- edge scatter: AGG[dst] += norm * H[src] ----------------
// one float4 per thread; M/4 threads per edge.
template <int M>
__global__ void k_scatter(const int* __restrict__ src, const int* __restrict__ dst,
                          const float* __restrict__ norm, const float* __restrict__ H,
                          float* __restrict__ AGG) {
    constexpr int VPE = M / 4;  // float4s per edge
    int gid = blockIdx.x * blockDim.x + threadIdx.x;
    if (gid >= NE * VPE) return;
    int e = gid / VPE;
    int q = gid - e * VPE;
    int s = src[e], d = dst[e];
    float nv = norm[e];
    float4 v = ((const float4*)(H + (long long)s * M))[q];
    float* o = AGG + (long long)d * M + q * 4;
    atomicAdd(o + 0, nv * v.x);
    atomicAdd(o + 1, nv * v.y);
    atomicAdd(o + 2, nv * v.z);
    atomicAdd(o + 3, nv * v.w);
}

// ---------------- finalize layer 1: relu(agg + dinv^2*h + b), in place ----------------
__global__ void k_fin1(float* __restrict__ AGG, const float* __restrict__ H,
                       const float* __restrict__ dinv, const float* __restrict__ b) {
    int gid = blockIdx.x * blockDim.x + threadIdx.x;
    if (gid >= NN * 128) return;
    int i = gid >> 7, c = gid & 127;
    float di = dinv[i];
    float v = AGG[gid] + di * di * H[gid] + b[c];
    AGG[gid] = fmaxf(v, 0.0f);
}

// ---------------- finalize layer 2 + log_softmax (one wave per row) ----------------
__global__ void k_fin2_lsm(const float* __restrict__ AGG2, const float* __restrict__ H2,
                           const float* __restrict__ dinv, const float* __restrict__ b,
                           float* __restrict__ OUT) {
    int row = blockIdx.x * (blockDim.x >> 6) + (threadIdx.x >> 6);
    int c = threadIdx.x & 63;
    if (row >= NN) return;
    float di = dinv[row];
    long long idx = (long long)row * 64 + c;
    float v = AGG2[idx] + di * di * H2[idx] + b[c];
    float m = v;
#pragma unroll
    for (int o = 32; o > 0; o >>= 1) m = fmaxf(m, __shfl_xor(m, o));
    float ex = expf(v - m);
    float sum = ex;
#pragma unroll
    for (int o = 32; o > 0; o >>= 1) sum += __shfl_xor(sum, o);
    OUT[idx] = v - m - logf(sum);
}

extern "C" void kernel_launch(void* const* d_in, const int* in_sizes, int n_in,
                              void* d_out, int out_size, void* d_ws, size_t ws_size,
                              hipStream_t stream) {
    const float* x = (const float*)d_in[0];
    const int* ei = (const int*)d_in[1];  // [2, NE], harness passes integers as int32
    const float* W1 = (const float*)d_in[2];
    const float* b1 = (const float*)d_in[3];
    const float* W2 = (const float*)d_in[4];
    const float* b2 = (const float*)d_in[5];
    float* out = (float*)d_out;

    const int* src = ei;       // edge_index[0]
    const int* dst = ei + NE;  // edge_index[1]

    // workspace layout (floats)
    float* dinv = (float*)d_ws;               // NN      (deg -> dinv in place)
    float* bufA = dinv + NN;                  // NN*128  (h1; later h2 in first NN*64)
    float* bufB = bufA + (size_t)NN * 128;    // NN*128  (agg1 -> x2 in place)
    float* agg2 = bufB + (size_t)NN * 128;    // NN*64
    float* norm = agg2 + (size_t)NN * 64;     // NE

    k_init<<<2048, 256, 0, stream>>>(dinv, bufB, agg2);
    k_deg<<<(NE + 255) / 256, 256, 0, stream>>>(dst, dinv);
    k_rsqrt<<<(NN + 255) / 256, 256, 0, stream>>>(dinv);
    k_edgeprep<<<(NE + 255) / 256, 256, 0, stream>>>(src, dst, dinv, norm);

    // layer 1
    k_gemm<128><<<NN / 8, 128, 0, stream>>>(x, W1, bufA);
    k_scatter<128><<<(NE * 32 + 255) / 256, 256, 0, stream>>>(src, dst, norm, bufA, bufB);
    k_fin1<<<(NN * 128 + 255) / 256, 256, 0, stream>>>(bufB, bufA, dinv, b1);

    // layer 2
    k_gemm<64><<<NN / 8, 64, 0, stream>>>(bufB, W2, bufA);
    k_scatter<64><<<(NE * 16 + 255) / 256, 256, 0, stream>>>(src, dst, norm, bufA, agg2);
    k_fin2_lsm<<<(NN + 3) / 4, 256, 0, stream>>>(agg2, bufA, dinv, b2, out);
}

// Round 3
// 258.279 us; speedup vs baseline: 8.2931x; 8.2931x over previous
//
#include <hip/hip_runtime.h>

#define NN 50000
#define NE 800000
#define SCAN_B 512
#define NSCAN ((NN + SCAN_B - 1) / SCAN_B)  // 98 blocks

// ---------------- zero int degree counters ----------------
__global__ void k_zero(int* __restrict__ degi) {
    int i = blockIdx.x * blockDim.x + threadIdx.x;
    if (i < NN) degi[i] = 0;
}

// ---------------- in-degree count at dst (int atomics) ----------------
__global__ void k_deg(const int* __restrict__ dst, int* __restrict__ degi) {
    int e = blockIdx.x * blockDim.x + threadIdx.x;
    if (e < NE) atomicAdd(&degi[dst[e]], 1);
}

// ---------------- dinv = rsqrt(deg + 1 self-loop) ----------------
__global__ void k_dinv(const int* __restrict__ degi, float* __restrict__ dinv) {
    int i = blockIdx.x * blockDim.x + threadIdx.x;
    if (i < NN) dinv[i] = rsqrtf((float)(degi[i] + 1));
}

// ---------------- 3-phase exclusive scan of degi -> row_start, cursor ----------------
__global__ void k_scanA(const int* __restrict__ degi, int* __restrict__ bsum) {
    __shared__ int s[SCAN_B];
    int t = threadIdx.x, g = blockIdx.x * SCAN_B + t;
    s[t] = (g < NN) ? degi[g] : 0;
    __syncthreads();
    for (int o = SCAN_B / 2; o > 0; o >>= 1) {
        if (t < o) s[t] += s[t + o];
        __syncthreads();
    }
    if (t == 0) bsum[blockIdx.x] = s[0];
}

__global__ void k_scanB(int* __restrict__ bsum) {  // single block of 128, nb=NSCAN<=128
    __shared__ int s[128];
    int t = threadIdx.x;
    int v = (t < NSCAN) ? bsum[t] : 0;
    s[t] = v;
    __syncthreads();
    for (int o = 1; o < 128; o <<= 1) {
        int a = (t >= o) ? s[t - o] : 0;
        __syncthreads();
        s[t] += a;
        __syncthreads();
    }
    if (t < NSCAN) bsum[t] = s[t] - v;  // exclusive
}

__global__ void k_scanC(const int* __restrict__ degi, const int* __restrict__ bsum,
                        int* __restrict__ row_start, int* __restrict__ cursor) {
    __shared__ int s[SCAN_B];
    int t = threadIdx.x, g = blockIdx.x * SCAN_B + t;
    int v = (g < NN) ? degi[g] : 0;
    s[t] = v;
    __syncthreads();
    for (int o = 1; o < SCAN_B; o <<= 1) {
        int a = (t >= o) ? s[t - o] : 0;
        __syncthreads();
        s[t] += a;
        __syncthreads();
    }
    if (g < NN) {
        int excl = s[t] - v + bsum[blockIdx.x];
        row_start[g] = excl;
        cursor[g] = excl;
    }
}

// ---------------- fill CSR: edges sorted by dst, with precomputed norm ----------------
__global__ void k_fill(const int* __restrict__ src, const int* __restrict__ dst,
                       const float* __restrict__ dinv, int* __restrict__ cursor,
                       int* __restrict__ esrc, float* __restrict__ enorm) {
    int e = blockIdx.x * blockDim.x + threadIdx.x;
    if (e >= NE) return;
    int s = src[e], d = dst[e];
    int pos = atomicAdd(&cursor[d], 1);
    esrc[pos] = s;
    enorm[pos] = dinv[s] * dinv[d];
}

// ---------------- f32 GEMM: H[N,M] = X[N,128] @ W[128,M] ----------------
template <int M>
__global__ void k_gemm(const float* __restrict__ X, const float* __restrict__ W,
                       float* __restrict__ H) {
    __shared__ float xs[8][128];
    const int c = threadIdx.x;
    const int r0 = blockIdx.x * 8;
    for (int idx = threadIdx.x; idx < 8 * 128; idx += M) {
        int r = idx >> 7, k = idx & 127;
        xs[r][k] = X[(long long)(r0 + r) * 128 + k];
    }
    __syncthreads();
    float acc[8];
#pragma unroll
    for (int r = 0; r < 8; ++r) acc[r] = 0.0f;
#pragma unroll 4
    for (int k = 0; k < 128; ++k) {
        float wv = W[k * M + c];
#pragma unroll
        for (int r = 0; r < 8; ++r) acc[r] = fmaf(xs[r][k], wv, acc[r]);
    }
#pragma unroll
    for (int r = 0; r < 8; ++r)
        H[(long long)(r0 + r) * M + c] = acc[r];
}

// ---------------- layer-1 aggregate (gather CSR) + self + bias + relu ----------------
// one wave per node; lane handles 2 cols as float2. X2[i] = relu(sum + dinv^2*h + b)
__global__ void k_agg1(const int* __restrict__ row_start, const int* __restrict__ degi,
                       const int* __restrict__ esrc, const float* __restrict__ enorm,
                       const float* __restrict__ H, const float* __restrict__ dinv,
                       const float* __restrict__ b, float* __restrict__ X2) {
    int wid = (blockIdx.x * blockDim.x + threadIdx.x) >> 6;
    int lane = threadIdx.x & 63;
    if (wid >= NN) return;
    const float2* Hp = (const float2*)H;  // row stride 64 float2
    int beg = row_start[wid], n = degi[wid];
    float ax = 0.0f, ay = 0.0f;
    int j = 0;
    for (; j + 4 <= n; j += 4) {
        int s0 = esrc[beg + j + 0], s1 = esrc[beg + j + 1];
        int s2 = esrc[beg + j + 2], s3 = esrc[beg + j + 3];
        float n0 = enorm[beg + j + 0], n1 = enorm[beg + j + 1];
        float n2 = enorm[beg + j + 2], n3 = enorm[beg + j + 3];
        float2 v0 = Hp[(size_t)s0 * 64 + lane];
        float2 v1 = Hp[(size_t)s1 * 64 + lane];
        float2 v2 = Hp[(size_t)s2 * 64 + lane];
        float2 v3 = Hp[(size_t)s3 * 64 + lane];
        ax = fmaf(n0, v0.x, ax); ay = fmaf(n0, v0.y, ay);
        ax = fmaf(n1, v1.x, ax); ay = fmaf(n1, v1.y, ay);
        ax = fmaf(n2, v2.x, ax); ay = fmaf(n2, v2.y, ay);
        ax = fmaf(n3, v3.x, ax); ay = fmaf(n3, v3.y, ay);
    }
    for (; j < n; ++j) {
        int s = esrc[beg + j];
        float nv = enorm[beg + j];
        float2 v = Hp[(size_t)s * 64 + lane];
        ax = fmaf(nv, v.x, ax); ay = fmaf(nv, v.y, ay);
    }
    float di = dinv[wid];
    float sw = di * di;
    float2 hv = Hp[(size_t)wid * 64 + lane];
    float2 bv = ((const float2*)b)[lane];
    ax = fmaf(sw, hv.x, ax) + bv.x;
    ay = fmaf(sw, hv.y, ay) + bv.y;
    float2 o;
    o.x = fmaxf(ax, 0.0f);
    o.y = fmaxf(ay, 0.0f);
    ((float2*)X2)[(size_t)wid * 64 + lane] = o;
}

// ---------------- layer-2 aggregate + self + bias + log_softmax ----------------
__global__ void k_agg2_lsm(const int* __restrict__ row_start, const int* __restrict__ degi,
                           const int* __restrict__ esrc, const float* __restrict__ enorm,
                           const float* __restrict__ H2, const float* __restrict__ dinv,
                           const float* __restrict__ b, float* __restrict__ OUT) {
    int wid = (blockIdx.x * blockDim.x + threadIdx.x) >> 6;
    int lane = threadIdx.x & 63;
    if (wid >= NN) return;
    int beg = row_start[wid], n = degi[wid];
    float acc = 0.0f;
    int j = 0;
    for (; j + 4 <= n; j += 4) {
        int s0 = esrc[beg + j + 0], s1 = esrc[beg + j + 1];
        int s2 = esrc[beg + j + 2], s3 = esrc[beg + j + 3];
        float n0 = enorm[beg + j + 0], n1 = enorm[beg + j + 1];
        float n2 = enorm[beg + j + 2], n3 = enorm[beg + j + 3];
        acc = fmaf(n0, H2[(size_t)s0 * 64 + lane], acc);
        acc = fmaf(n1, H2[(size_t)s1 * 64 + lane], acc);
        acc = fmaf(n2, H2[(size_t)s2 * 64 + lane], acc);
        acc = fmaf(n3, H2[(size_t)s3 * 64 + lane], acc);
    }
    for (; j < n; ++j) {
        acc = fmaf(enorm[beg + j], H2[(size_t)esrc[beg + j] * 64 + lane], acc);
    }
    float di = dinv[wid];
    acc = fmaf(di * di, H2[(size_t)wid * 64 + lane], acc) + b[lane];
    float m = acc;
#pragma unroll
    for (int o = 32; o > 0; o >>= 1) m = fmaxf(m, __shfl_xor(m, o));
    float ex = expf(acc - m);
    float sum = ex;
#pragma unroll
    for (int o = 32; o > 0; o >>= 1) sum += __shfl_xor(sum, o);
    OUT[(size_t)wid * 64 + lane] = acc - m - logf(sum);
}

extern "C" void kernel_launch(void* const* d_in, const int* in_sizes, int n_in,
                              void* d_out, int out_size, void* d_ws, size_t ws_size,
                              hipStream_t stream) {
    const float* x = (const float*)d_in[0];
    const int* ei = (const int*)d_in[1];  // [2, NE] int32
    const float* W1 = (const float*)d_in[2];
    const float* b1 = (const float*)d_in[3];
    const float* W2 = (const float*)d_in[4];
    const float* b2 = (const float*)d_in[5];
    float* out = (float*)d_out;

    const int* src = ei;
    const int* dst = ei + NE;

    // workspace layout
    int* degi = (int*)d_ws;                      // NN
    float* dinv = (float*)(degi + NN);           // NN
    int* row_start = (int*)(dinv + NN);          // NN
    int* cursor = row_start + NN;                // NN
    int* bsum = cursor + NN;                     // 128
    int* esrc = bsum + 128;                      // NE
    float* enorm = (float*)(esrc + NE);          // NE
    float* bufA = enorm + NE;                    // NN*128 (h1, then h2 in first NN*64)
    float* bufB = bufA + (size_t)NN * 128;       // NN*128 (x2)

    k_zero<<<(NN + 255) / 256, 256, 0, stream>>>(degi);
    k_deg<<<(NE + 255) / 256, 256, 0, stream>>>(dst, degi);
    k_dinv<<<(NN + 255) / 256, 256, 0, stream>>>(degi, dinv);
    k_scanA<<<NSCAN, SCAN_B, 0, stream>>>(degi, bsum);
    k_scanB<<<1, 128, 0, stream>>>(bsum);
    k_scanC<<<NSCAN, SCAN_B, 0, stream>>>(degi, bsum, row_start, cursor);
    k_fill<<<(NE + 255) / 256, 256, 0, stream>>>(src, dst, dinv, cursor, esrc, enorm);

    // layer 1
    k_gemm<128><<<NN / 8, 128, 0, stream>>>(x, W1, bufA);
    k_agg1<<<(NN * 64 + 255) / 256, 256, 0, stream>>>(row_start, degi, esrc, enorm,
                                                      bufA, dinv, b1, bufB);
    // layer 2
    k_gemm<64><<<NN / 8, 64, 0, stream>>>(bufB, W2, bufA);
    k_agg2_lsm<<<(NN * 64 + 255) / 256, 256, 0, stream>>>(row_start, degi, esrc, enorm,
                                                          bufA, dinv, b2, out);
}

// Round 4
// 243.250 us; speedup vs baseline: 8.8055x; 1.0618x over previous
//
#include <hip/hip_runtime.h>

#define NN 50000
#define NE 800000
#define SCAN_B 512
#define NSCAN ((NN + SCAN_B - 1) / SCAN_B)  // 98 blocks

__device__ __forceinline__ unsigned pack_bf16x2(float a, float b) {
    unsigned ua = __float_as_uint(a);
    unsigned ub = __float_as_uint(b);
    ua = (ua + 0x7FFFu + ((ua >> 16) & 1u)) >> 16;
    ub = (ub + 0x7FFFu + ((ub >> 16) & 1u)) >> 16;
    return ua | (ub << 16);
}
__device__ __forceinline__ float bf16_lo(unsigned u) { return __uint_as_float(u << 16); }
__device__ __forceinline__ float bf16_hi(unsigned u) { return __uint_as_float(u & 0xFFFF0000u); }

// ---------------- prep ----------------
__global__ void k_zero(int* __restrict__ degi) {
    int i = blockIdx.x * blockDim.x + threadIdx.x;
    if (i < NN) degi[i] = 0;
}

__global__ void k_deg(const int* __restrict__ dst, int* __restrict__ degi) {
    int e = blockIdx.x * blockDim.x + threadIdx.x;
    if (e < NE) atomicAdd(&degi[dst[e]], 1);
}

__global__ void k_dinv(const int* __restrict__ degi, float* __restrict__ dinv) {
    int i = blockIdx.x * blockDim.x + threadIdx.x;
    if (i < NN) dinv[i] = rsqrtf((float)(degi[i] + 1));
}

__global__ void k_scanA(const int* __restrict__ degi, int* __restrict__ bsum) {
    __shared__ int s[SCAN_B];
    int t = threadIdx.x, g = blockIdx.x * SCAN_B + t;
    s[t] = (g < NN) ? degi[g] : 0;
    __syncthreads();
    for (int o = SCAN_B / 2; o > 0; o >>= 1) {
        if (t < o) s[t] += s[t + o];
        __syncthreads();
    }
    if (t == 0) bsum[blockIdx.x] = s[0];
}

__global__ void k_scanB(int* __restrict__ bsum) {  // 1 block of 128; NSCAN<=128
    __shared__ int s[128];
    int t = threadIdx.x;
    int v = (t < NSCAN) ? bsum[t] : 0;
    s[t] = v;
    __syncthreads();
    for (int o = 1; o < 128; o <<= 1) {
        int a = (t >= o) ? s[t - o] : 0;
        __syncthreads();
        s[t] += a;
        __syncthreads();
    }
    if (t < NSCAN) bsum[t] = s[t] - v;  // exclusive
}

__global__ void k_scanC(const int* __restrict__ degi, const int* __restrict__ bsum,
                        int* __restrict__ row_start, int* __restrict__ cursor) {
    __shared__ int s[SCAN_B];
    int t = threadIdx.x, g = blockIdx.x * SCAN_B + t;
    int v = (g < NN) ? degi[g] : 0;
    s[t] = v;
    __syncthreads();
    for (int o = 1; o < SCAN_B; o <<= 1) {
        int a = (t >= o) ? s[t - o] : 0;
        __syncthreads();
        s[t] += a;
        __syncthreads();
    }
    if (g < NN) {
        int excl = s[t] - v + bsum[blockIdx.x];
        row_start[g] = excl;
        cursor[g] = excl;
    }
}

__global__ void k_fill(const int* __restrict__ src, const int* __restrict__ dst,
                       int* __restrict__ cursor, int* __restrict__ esrc) {
    int e = blockIdx.x * blockDim.x + threadIdx.x;
    if (e >= NE) return;
    int pos = atomicAdd(&cursor[dst[e]], 1);
    esrc[pos] = src[e];
}

// ---------------- GEMM1: Hb[N,64 uint] = pack_bf16(dinv[r] * (X[N,128] @ W[128,128])) ----------------
// 256 threads, 32-row tile; thread = (rg = t>>6 in [0,4), cp = t&63) -> 8 rows x 2 cols.
__global__ void k_gemm1(const float* __restrict__ X, const float* __restrict__ W,
                        const float* __restrict__ dinv, unsigned* __restrict__ Hb) {
    __shared__ float xs[32][128];
    const int t = threadIdx.x;
    const int r0 = blockIdx.x * 32;
    const int cp = t & 63, rg = t >> 6;
    // stage 32x128 floats as float4 (4 per thread)
    for (int i = 0; i < 4; ++i) {
        int idx = t + i * 256;             // float4 index
        int r = idx >> 5, c4 = idx & 31;   // 32 float4 per row
        float4 v = (r0 + r < NN) ? ((const float4*)(X + (size_t)(r0 + r) * 128))[c4]
                                 : make_float4(0.f, 0.f, 0.f, 0.f);
        ((float4*)&xs[r][0])[c4] = v;
    }
    __syncthreads();
    float2 acc[8];
#pragma unroll
    for (int r = 0; r < 8; ++r) acc[r] = make_float2(0.f, 0.f);
#pragma unroll 4
    for (int k = 0; k < 128; ++k) {
        float2 wv = ((const float2*)(W + k * 128))[cp];
#pragma unroll
        for (int r = 0; r < 8; ++r) {
            float xv = xs[rg * 8 + r][k];
            acc[r].x = fmaf(xv, wv.x, acc[r].x);
            acc[r].y = fmaf(xv, wv.y, acc[r].y);
        }
    }
#pragma unroll
    for (int r = 0; r < 8; ++r) {
        int row = r0 + rg * 8 + r;
        if (row < NN) {
            float s = dinv[row];
            Hb[(size_t)row * 64 + cp] = pack_bf16x2(acc[r].x * s, acc[r].y * s);
        }
    }
}

// ---------------- GEMM2: Hb2[N,32 uint] = pack_bf16(dinv[r] * (X2[N,128] @ W2[128,64])) ----------------
// 256 threads, 32-row tile; thread = (rg = t>>5 in [0,8), cp = t&31) -> 4 rows x 2 cols.
__global__ void k_gemm2(const float* __restrict__ X, const float* __restrict__ W,
                        const float* __restrict__ dinv, unsigned* __restrict__ Hb) {
    __shared__ float xs[32][128];
    const int t = threadIdx.x;
    const int r0 = blockIdx.x * 32;
    const int cp = t & 31, rg = t >> 5;
    for (int i = 0; i < 4; ++i) {
        int idx = t + i * 256;
        int r = idx >> 5, c4 = idx & 31;
        float4 v = (r0 + r < NN) ? ((const float4*)(X + (size_t)(r0 + r) * 128))[c4]
                                 : make_float4(0.f, 0.f, 0.f, 0.f);
        ((float4*)&xs[r][0])[c4] = v;
    }
    __syncthreads();
    float2 acc[4];
#pragma unroll
    for (int r = 0; r < 4; ++r) acc[r] = make_float2(0.f, 0.f);
#pragma unroll 4
    for (int k = 0; k < 128; ++k) {
        float2 wv = ((const float2*)(W + k * 64))[cp];
#pragma unroll
        for (int r = 0; r < 4; ++r) {
            float xv = xs[rg * 4 + r][k];
            acc[r].x = fmaf(xv, wv.x, acc[r].x);
            acc[r].y = fmaf(xv, wv.y, acc[r].y);
        }
    }
#pragma unroll
    for (int r = 0; r < 4; ++r) {
        int row = r0 + rg * 4 + r;
        if (row < NN) {
            float s = dinv[row];
            Hb[(size_t)row * 32 + cp] = pack_bf16x2(acc[r].x * s, acc[r].y * s);
        }
    }
}

// ---------------- layer-1 aggregate: X2 = relu(dinv_d * (sum Hb'[s] + Hb'[d]) + b) ----------------
// one wave per node; lane = 2 cols (one packed uint). Hb rows are 64 uints (256B).
__global__ void k_agg1(const int* __restrict__ row_start, const int* __restrict__ degi,
                       const int* __restrict__ esrc, const unsigned* __restrict__ Hb,
                       const float* __restrict__ dinv, const float* __restrict__ b,
                       float* __restrict__ X2) {
    int wid = (blockIdx.x * blockDim.x + threadIdx.x) >> 6;
    int lane = threadIdx.x & 63;
    if (wid >= NN) return;
    int beg = row_start[wid], n = degi[wid];
    float ax = 0.f, ay = 0.f;
    int j = 0;
    for (; j + 4 <= n; j += 4) {
        int s0 = esrc[beg + j + 0], s1 = esrc[beg + j + 1];
        int s2 = esrc[beg + j + 2], s3 = esrc[beg + j + 3];
        unsigned v0 = Hb[(size_t)s0 * 64 + lane];
        unsigned v1 = Hb[(size_t)s1 * 64 + lane];
        unsigned v2 = Hb[(size_t)s2 * 64 + lane];
        unsigned v3 = Hb[(size_t)s3 * 64 + lane];
        ax += bf16_lo(v0) + bf16_lo(v1) + bf16_lo(v2) + bf16_lo(v3);
        ay += bf16_hi(v0) + bf16_hi(v1) + bf16_hi(v2) + bf16_hi(v3);
    }
    for (; j < n; ++j) {
        unsigned v = Hb[(size_t)esrc[beg + j] * 64 + lane];
        ax += bf16_lo(v);
        ay += bf16_hi(v);
    }
    unsigned vs = Hb[(size_t)wid * 64 + lane];  // self-loop
    ax += bf16_lo(vs);
    ay += bf16_hi(vs);
    float di = dinv[wid];
    float2 bv = ((const float2*)b)[lane];
    float2 o;
    o.x = fmaxf(fmaf(di, ax, bv.x), 0.f);
    o.y = fmaxf(fmaf(di, ay, bv.y), 0.f);
    ((float2*)X2)[(size_t)wid * 64 + lane] = o;
}

// ---------------- layer-2 aggregate + log_softmax ----------------
// one wave per node; lane = 1 col (ushort). Hb2 rows are 64 ushorts (128B).
__global__ void k_agg2_lsm(const int* __restrict__ row_start, const int* __restrict__ degi,
                           const int* __restrict__ esrc, const unsigned short* __restrict__ Hb,
                           const float* __restrict__ dinv, const float* __restrict__ b,
                           float* __restrict__ OUT) {
    int wid = (blockIdx.x * blockDim.x + threadIdx.x) >> 6;
    int lane = threadIdx.x & 63;
    if (wid >= NN) return;
    int beg = row_start[wid], n = degi[wid];
    float acc = 0.f;
    int j = 0;
    for (; j + 4 <= n; j += 4) {
        int s0 = esrc[beg + j + 0], s1 = esrc[beg + j + 1];
        int s2 = esrc[beg + j + 2], s3 = esrc[beg + j + 3];
        float v0 = __uint_as_float((unsigned)Hb[(size_t)s0 * 64 + lane] << 16);
        float v1 = __uint_as_float((unsigned)Hb[(size_t)s1 * 64 + lane] << 16);
        float v2 = __uint_as_float((unsigned)Hb[(size_t)s2 * 64 + lane] << 16);
        float v3 = __uint_as_float((unsigned)Hb[(size_t)s3 * 64 + lane] << 16);
        acc += v0 + v1 + v2 + v3;
    }
    for (; j < n; ++j)
        acc += __uint_as_float((unsigned)Hb[(size_t)esrc[beg + j] * 64 + lane] << 16);
    acc += __uint_as_float((unsigned)Hb[(size_t)wid * 64 + lane] << 16);  // self
    float v = fmaf(dinv[wid], acc, b[lane]);
    float m = v;
#pragma unroll
    for (int o = 32; o > 0; o >>= 1) m = fmaxf(m, __shfl_xor(m, o));
    float ex = expf(v - m);
    float sum = ex;
#pragma unroll
    for (int o = 32; o > 0; o >>= 1) sum += __shfl_xor(sum, o);
    OUT[(size_t)wid * 64 + lane] = v - m - logf(sum);
}

extern "C" void kernel_launch(void* const* d_in, const int* in_sizes, int n_in,
                              void* d_out, int out_size, void* d_ws, size_t ws_size,
                              hipStream_t stream) {
    const float* x = (const float*)d_in[0];
    const int* ei = (const int*)d_in[1];  // [2, NE] int32
    const float* W1 = (const float*)d_in[2];
    const float* b1 = (const float*)d_in[3];
    const float* W2 = (const float*)d_in[4];
    const float* b2 = (const float*)d_in[5];
    float* out = (float*)d_out;

    const int* src = ei;
    const int* dst = ei + NE;

    // workspace layout
    int* degi = (int*)d_ws;                      // NN
    float* dinv = (float*)(degi + NN);           // NN
    int* row_start = (int*)(dinv + NN);          // NN
    int* cursor = row_start + NN;                // NN
    int* bsum = cursor + NN;                     // 128
    int* esrc = bsum + 128;                      // NE
    unsigned* H1b = (unsigned*)(esrc + NE);      // NN*64  (bf16x2 packed, 12.8MB)
    unsigned* H2b = H1b + (size_t)NN * 64;       // NN*32  (bf16x2 packed, 6.4MB)
    float* X2 = (float*)(H2b + (size_t)NN * 32); // NN*128 f32

    k_zero<<<(NN + 255) / 256, 256, 0, stream>>>(degi);
    k_deg<<<(NE + 255) / 256, 256, 0, stream>>>(dst, degi);
    k_dinv<<<(NN + 255) / 256, 256, 0, stream>>>(degi, dinv);
    k_scanA<<<NSCAN, SCAN_B, 0, stream>>>(degi, bsum);
    k_scanB<<<1, 128, 0, stream>>>(bsum);
    k_scanC<<<NSCAN, SCAN_B, 0, stream>>>(degi, bsum, row_start, cursor);
    k_fill<<<(NE + 255) / 256, 256, 0, stream>>>(src, dst, cursor, esrc);

    // layer 1
    k_gemm1<<<(NN + 31) / 32, 256, 0, stream>>>(x, W1, dinv, H1b);
    k_agg1<<<(NN * 64 + 255) / 256, 256, 0, stream>>>(row_start, degi, esrc, H1b, dinv, b1, X2);
    // layer 2
    k_gemm2<<<(NN + 31) / 32, 256, 0, stream>>>(X2, W2, dinv, H2b);
    k_agg2_lsm<<<(NN * 64 + 255) / 256, 256, 0, stream>>>(row_start, degi, esrc,
                                                          (const unsigned short*)H2b, dinv, b2, out);
}

// Round 5
// 224.588 us; speedup vs baseline: 9.5372x; 1.0831x over previous
//
#include <hip/hip_runtime.h>

#define NN 50000
#define NE 800000
#define SCAN_B 512
#define NSCAN ((NN + SCAN_B - 1) / SCAN_B)  // 98 blocks
#define NB 391                              // dst buckets of 128 nodes
#define CHUNK 8192                          // edges per pass-1 block
#define NCH ((NE + CHUNK - 1) / CHUNK)      // 98 blocks

__device__ __forceinline__ unsigned pack_bf16x2(float a, float b) {
    unsigned ua = __float_as_uint(a);
    unsigned ub = __float_as_uint(b);
    ua = (ua + 0x7FFFu + ((ua >> 16) & 1u)) >> 16;
    ub = (ub + 0x7FFFu + ((ub >> 16) & 1u)) >> 16;
    return ua | (ub << 16);
}
__device__ __forceinline__ float bf16_lo(unsigned u) { return __uint_as_float(u << 16); }
__device__ __forceinline__ float bf16_hi(unsigned u) { return __uint_as_float(u & 0xFFFF0000u); }

// ---------------- prep ----------------
__global__ void k_zero(int* __restrict__ degi) {
    int i = blockIdx.x * blockDim.x + threadIdx.x;
    if (i < NN) degi[i] = 0;
}

__global__ void k_deg(const int* __restrict__ dst, int* __restrict__ degi) {
    int e = blockIdx.x * blockDim.x + threadIdx.x;
    if (e < NE) atomicAdd(&degi[dst[e]], 1);
}

// scanA: block-sums of degi (+ fused dinv)
__global__ void k_scanA(const int* __restrict__ degi, int* __restrict__ bsum,
                        float* __restrict__ dinv) {
    __shared__ int s[SCAN_B];
    int t = threadIdx.x, g = blockIdx.x * SCAN_B + t;
    int v = (g < NN) ? degi[g] : 0;
    if (g < NN) dinv[g] = rsqrtf((float)(v + 1));  // +1 self-loop
    s[t] = v;
    __syncthreads();
    for (int o = SCAN_B / 2; o > 0; o >>= 1) {
        if (t < o) s[t] += s[t + o];
        __syncthreads();
    }
    if (t == 0) bsum[blockIdx.x] = s[0];
}

__global__ void k_scanB(int* __restrict__ bsum) {  // 1 block of 128; NSCAN<=128
    __shared__ int s[128];
    int t = threadIdx.x;
    int v = (t < NSCAN) ? bsum[t] : 0;
    s[t] = v;
    __syncthreads();
    for (int o = 1; o < 128; o <<= 1) {
        int a = (t >= o) ? s[t - o] : 0;
        __syncthreads();
        s[t] += a;
        __syncthreads();
    }
    if (t < NSCAN) bsum[t] = s[t] - v;  // exclusive
}

// scanC: exclusive scan -> row_start (+ fused bucket cursor init)
__global__ void k_scanC(const int* __restrict__ degi, const int* __restrict__ bsum,
                        int* __restrict__ row_start, int* __restrict__ bcur) {
    __shared__ int s[SCAN_B];
    int t = threadIdx.x, g = blockIdx.x * SCAN_B + t;
    int v = (g < NN) ? degi[g] : 0;
    s[t] = v;
    __syncthreads();
    for (int o = 1; o < SCAN_B; o <<= 1) {
        int a = (t >= o) ? s[t - o] : 0;
        __syncthreads();
        s[t] += a;
        __syncthreads();
    }
    if (g < NN) {
        int excl = s[t] - v + bsum[blockIdx.x];
        row_start[g] = excl;
        if ((g & 127) == 0) bcur[g >> 7] = excl;  // bucket base
    }
}

// ---------------- pass 1: bucket-bin edges (LDS histogram, run-coalesced writes) ----------------
// packed edge: [31:23]=bucket, [22:16]=dst&127, [15:0]=src
__global__ void k_scat1(const int* __restrict__ src, const int* __restrict__ dst,
                        int* __restrict__ bcur, unsigned* __restrict__ eord) {
    __shared__ int hist[NB];
    __shared__ int gbase[NB];
    const int t = threadIdx.x;
    const int e0 = blockIdx.x * CHUNK;
    for (int j = t; j < NB; j += 256) hist[j] = 0;
    __syncthreads();
    unsigned pk[32];
#pragma unroll
    for (int i = 0; i < 32; ++i) {
        int e = e0 + t + i * 256;
        pk[i] = 0xFFFFFFFFu;
        if (e < NE) {
            unsigned s = (unsigned)src[e];
            unsigned d = (unsigned)dst[e];
            unsigned bk = d >> 7;
            pk[i] = (bk << 23) | ((d & 127u) << 16) | s;
            atomicAdd(&hist[bk], 1);
        }
    }
    __syncthreads();
    for (int j = t; j < NB; j += 256) {
        int c = hist[j];
        gbase[j] = c ? atomicAdd(&bcur[j], c) : 0;
        hist[j] = 0;  // reuse as within-block cursor
    }
    __syncthreads();
#pragma unroll
    for (int i = 0; i < 32; ++i) {
        if (pk[i] != 0xFFFFFFFFu) {
            int bk = pk[i] >> 23;
            int pos = gbase[bk] + atomicAdd(&hist[bk], 1);
            eord[pos] = pk[i];
        }
    }
}

// ---------------- pass 2: within-bucket exact sort -> esrc16 ----------------
__global__ void k_scat2(const int* __restrict__ row_start, const unsigned* __restrict__ eord,
                        unsigned short* __restrict__ esrc16) {
    __shared__ int cur[128];
    const int b = blockIdx.x;
    const int t = threadIdx.x;
    const int d0 = b << 7;
    if (t < 128) {
        int d = d0 + t;
        cur[t] = (d < NN) ? row_start[d] : 0;
    }
    __syncthreads();
    const int beg = row_start[d0];
    const int end = (d0 + 128 < NN) ? row_start[d0 + 128] : NE;
    for (int i = beg + t; i < end; i += 256) {
        unsigned v = eord[i];
        int d7 = (v >> 16) & 127;
        int pos = atomicAdd(&cur[d7], 1);
        esrc16[pos] = (unsigned short)(v & 0xFFFFu);
    }
}

// ---------------- GEMM1: Hb[N,64 uint] = pack_bf16(dinv[r] * (X @ W1)) ----------------
__global__ void k_gemm1(const float* __restrict__ X, const float* __restrict__ W,
                        const float* __restrict__ dinv, unsigned* __restrict__ Hb) {
    __shared__ float xs[32][128];
    const int t = threadIdx.x;
    const int r0 = blockIdx.x * 32;
    const int cp = t & 63, rg = t >> 6;
    for (int i = 0; i < 4; ++i) {
        int idx = t + i * 256;
        int r = idx >> 5, c4 = idx & 31;
        float4 v = (r0 + r < NN) ? ((const float4*)(X + (size_t)(r0 + r) * 128))[c4]
                                 : make_float4(0.f, 0.f, 0.f, 0.f);
        ((float4*)&xs[r][0])[c4] = v;
    }
    __syncthreads();
    float2 acc[8];
#pragma unroll
    for (int r = 0; r < 8; ++r) acc[r] = make_float2(0.f, 0.f);
#pragma unroll 4
    for (int k = 0; k < 128; ++k) {
        float2 wv = ((const float2*)(W + k * 128))[cp];
#pragma unroll
        for (int r = 0; r < 8; ++r) {
            float xv = xs[rg * 8 + r][k];
            acc[r].x = fmaf(xv, wv.x, acc[r].x);
            acc[r].y = fmaf(xv, wv.y, acc[r].y);
        }
    }
#pragma unroll
    for (int r = 0; r < 8; ++r) {
        int row = r0 + rg * 8 + r;
        if (row < NN) {
            float s = dinv[row];
            Hb[(size_t)row * 64 + cp] = pack_bf16x2(acc[r].x * s, acc[r].y * s);
        }
    }
}

// ---------------- GEMM2: Hb2[N,32 uint] = pack_bf16(dinv[r] * (X2 @ W2)) ----------------
__global__ void k_gemm2(const float* __restrict__ X, const float* __restrict__ W,
                        const float* __restrict__ dinv, unsigned* __restrict__ Hb) {
    __shared__ float xs[32][128];
    const int t = threadIdx.x;
    const int r0 = blockIdx.x * 32;
    const int cp = t & 31, rg = t >> 5;
    for (int i = 0; i < 4; ++i) {
        int idx = t + i * 256;
        int r = idx >> 5, c4 = idx & 31;
        float4 v = (r0 + r < NN) ? ((const float4*)(X + (size_t)(r0 + r) * 128))[c4]
                                 : make_float4(0.f, 0.f, 0.f, 0.f);
        ((float4*)&xs[r][0])[c4] = v;
    }
    __syncthreads();
    float2 acc[4];
#pragma unroll
    for (int r = 0; r < 4; ++r) acc[r] = make_float2(0.f, 0.f);
#pragma unroll 4
    for (int k = 0; k < 128; ++k) {
        float2 wv = ((const float2*)(W + k * 64))[cp];
#pragma unroll
        for (int r = 0; r < 4; ++r) {
            float xv = xs[rg * 4 + r][k];
            acc[r].x = fmaf(xv, wv.x, acc[r].x);
            acc[r].y = fmaf(xv, wv.y, acc[r].y);
        }
    }
#pragma unroll
    for (int r = 0; r < 4; ++r) {
        int row = r0 + rg * 4 + r;
        if (row < NN) {
            float s = dinv[row];
            Hb[(size_t)row * 32 + cp] = pack_bf16x2(acc[r].x * s, acc[r].y * s);
        }
    }
}

// ---------------- layer-1 aggregate: X2 = relu(dinv_d * (sum Hb'[s] + Hb'[d]) + b) ----------------
__global__ void k_agg1(const int* __restrict__ row_start, const int* __restrict__ degi,
                       const unsigned short* __restrict__ esrc, const unsigned* __restrict__ Hb,
                       const float* __restrict__ dinv, const float* __restrict__ b,
                       float* __restrict__ X2) {
    int wid = (blockIdx.x * blockDim.x + threadIdx.x) >> 6;
    int lane = threadIdx.x & 63;
    if (wid >= NN) return;
    int beg = row_start[wid], n = degi[wid];
    float ax = 0.f, ay = 0.f;
    int j = 0;
    for (; j + 4 <= n; j += 4) {
        int s0 = esrc[beg + j + 0], s1 = esrc[beg + j + 1];
        int s2 = esrc[beg + j + 2], s3 = esrc[beg + j + 3];
        unsigned v0 = Hb[(size_t)s0 * 64 + lane];
        unsigned v1 = Hb[(size_t)s1 * 64 + lane];
        unsigned v2 = Hb[(size_t)s2 * 64 + lane];
        unsigned v3 = Hb[(size_t)s3 * 64 + lane];
        ax += bf16_lo(v0) + bf16_lo(v1) + bf16_lo(v2) + bf16_lo(v3);
        ay += bf16_hi(v0) + bf16_hi(v1) + bf16_hi(v2) + bf16_hi(v3);
    }
    for (; j < n; ++j) {
        unsigned v = Hb[(size_t)esrc[beg + j] * 64 + lane];
        ax += bf16_lo(v);
        ay += bf16_hi(v);
    }
    unsigned vs = Hb[(size_t)wid * 64 + lane];  // self-loop
    ax += bf16_lo(vs);
    ay += bf16_hi(vs);
    float di = dinv[wid];
    float2 bv = ((const float2*)b)[lane];
    float2 o;
    o.x = fmaxf(fmaf(di, ax, bv.x), 0.f);
    o.y = fmaxf(fmaf(di, ay, bv.y), 0.f);
    ((float2*)X2)[(size_t)wid * 64 + lane] = o;
}

// ---------------- layer-2 aggregate + log_softmax ----------------
__global__ void k_agg2_lsm(const int* __restrict__ row_start, const int* __restrict__ degi,
                           const unsigned short* __restrict__ esrc,
                           const unsigned short* __restrict__ Hb,
                           const float* __restrict__ dinv, const float* __restrict__ b,
                           float* __restrict__ OUT) {
    int wid = (blockIdx.x * blockDim.x + threadIdx.x) >> 6;
    int lane = threadIdx.x & 63;
    if (wid >= NN) return;
    int beg = row_start[wid], n = degi[wid];
    float acc = 0.f;
    int j = 0;
    for (; j + 4 <= n; j += 4) {
        int s0 = esrc[beg + j + 0], s1 = esrc[beg + j + 1];
        int s2 = esrc[beg + j + 2], s3 = esrc[beg + j + 3];
        float v0 = __uint_as_float((unsigned)Hb[(size_t)s0 * 64 + lane] << 16);
        float v1 = __uint_as_float((unsigned)Hb[(size_t)s1 * 64 + lane] << 16);
        float v2 = __uint_as_float((unsigned)Hb[(size_t)s2 * 64 + lane] << 16);
        float v3 = __uint_as_float((unsigned)Hb[(size_t)s3 * 64 + lane] << 16);
        acc += v0 + v1 + v2 + v3;
    }
    for (; j < n; ++j)
        acc += __uint_as_float((unsigned)Hb[(size_t)esrc[beg + j] * 64 + lane] << 16);
    acc += __uint_as_float((unsigned)Hb[(size_t)wid * 64 + lane] << 16);  // self
    float v = fmaf(dinv[wid], acc, b[lane]);
    float m = v;
#pragma unroll
    for (int o = 32; o > 0; o >>= 1) m = fmaxf(m, __shfl_xor(m, o));
    float ex = expf(v - m);
    float sum = ex;
#pragma unroll
    for (int o = 32; o > 0; o >>= 1) sum += __shfl_xor(sum, o);
    OUT[(size_t)wid * 64 + lane] = v - m - logf(sum);
}

extern "C" void kernel_launch(void* const* d_in, const int* in_sizes, int n_in,
                              void* d_out, int out_size, void* d_ws, size_t ws_size,
                              hipStream_t stream) {
    const float* x = (const float*)d_in[0];
    const int* ei = (const int*)d_in[1];  // [2, NE] int32
    const float* W1 = (const float*)d_in[2];
    const float* b1 = (const float*)d_in[3];
    const float* W2 = (const float*)d_in[4];
    const float* b2 = (const float*)d_in[5];
    float* out = (float*)d_out;

    const int* src = ei;
    const int* dst = ei + NE;

    // workspace layout
    int* degi = (int*)d_ws;                          // NN
    float* dinv = (float*)(degi + NN);               // NN
    int* row_start = (int*)(dinv + NN);              // NN
    int* bcur = row_start + NN;                      // NB
    int* bsum = bcur + NB;                           // 128
    unsigned* eord = (unsigned*)(bsum + 128);        // NE u32
    unsigned short* esrc16 = (unsigned short*)(eord + NE);  // NE u16
    unsigned* H1b = (unsigned*)(esrc16 + NE);        // NN*64 u32 (bf16x2)
    unsigned* H2b = H1b + (size_t)NN * 64;           // NN*32 u32 (bf16x2)
    float* X2 = (float*)(H2b + (size_t)NN * 32);     // NN*128 f32

    k_zero<<<(NN + 255) / 256, 256, 0, stream>>>(degi);
    k_deg<<<(NE + 255) / 256, 256, 0, stream>>>(dst, degi);
    k_scanA<<<NSCAN, SCAN_B, 0, stream>>>(degi, bsum, dinv);
    k_scanB<<<1, 128, 0, stream>>>(bsum);
    k_scanC<<<NSCAN, SCAN_B, 0, stream>>>(degi, bsum, row_start, bcur);
    k_scat1<<<NCH, 256, 0, stream>>>(src, dst, bcur, eord);
    k_scat2<<<NB, 256, 0, stream>>>(row_start, eord, esrc16);

    // layer 1
    k_gemm1<<<(NN + 31) / 32, 256, 0, stream>>>(x, W1, dinv, H1b);
    k_agg1<<<(NN * 64 + 255) / 256, 256, 0, stream>>>(row_start, degi, esrc16, H1b, dinv, b1, X2);
    // layer 2
    k_gemm2<<<(NN + 31) / 32, 256, 0, stream>>>(X2, W2, dinv, H2b);
    k_agg2_lsm<<<(NN * 64 + 255) / 256, 256, 0, stream>>>(row_start, degi, esrc16,
                                                          (const unsigned short*)H2b, dinv, b2, out);
}

// Round 6
// 177.815 us; speedup vs baseline: 12.0459x; 1.2630x over previous
//
#include <hip/hip_runtime.h>

#define NN 50000
#define NE 800000
#define NB 391            // dst buckets of 128 nodes (391*128 = 50048)
#define NBP 392           // padded
#define CHUNK 8192        // edges per pass-1 block
#define NCH ((NE + CHUNK - 1) / CHUNK)  // 98 blocks

__device__ __forceinline__ unsigned pack_bf16x2(float a, float b) {
    unsigned ua = __float_as_uint(a);
    unsigned ub = __float_as_uint(b);
    ua = (ua + 0x7FFFu + ((ua >> 16) & 1u)) >> 16;
    ub = (ub + 0x7FFFu + ((ub >> 16) & 1u)) >> 16;
    return ua | (ub << 16);
}
__device__ __forceinline__ float bf16_lo(unsigned u) { return __uint_as_float(u << 16); }
__device__ __forceinline__ float bf16_hi(unsigned u) { return __uint_as_float(u & 0xFFFF0000u); }

// ---------------- bucket histogram ----------------
__global__ void k_hist(const int* __restrict__ dst, int* __restrict__ bhist) {
    __shared__ int h[NB];
    const int t = threadIdx.x;
    for (int j = t; j < NB; j += 256) h[j] = 0;
    __syncthreads();
    const int e0 = blockIdx.x * CHUNK;
#pragma unroll 8
    for (int i = 0; i < 32; ++i) {
        int e = e0 + t + i * 256;
        if (e < NE) atomicAdd(&h[dst[e] >> 7], 1);
    }
    __syncthreads();
    for (int j = t; j < NB; j += 256)
        if (h[j]) atomicAdd(&bhist[j], h[j]);
}

// ---------------- bucket exclusive scan (1 block of 512) ----------------
__global__ void k_bscan(const int* __restrict__ bhist, int* __restrict__ bbase,
                        int* __restrict__ bcur) {
    __shared__ int s[512];
    int t = threadIdx.x;
    int v = (t < NB) ? bhist[t] : 0;
    s[t] = v;
    __syncthreads();
    for (int o = 1; o < 512; o <<= 1) {
        int a = (t >= o) ? s[t - o] : 0;
        __syncthreads();
        s[t] += a;
        __syncthreads();
    }
    if (t < NB) {
        int ex = s[t] - v;
        bbase[t] = ex;
        bcur[t] = ex;
    }
    if (t == 0) bbase[NB] = NE;
}

// ---------------- pass 1: bucket-bin edges ----------------
// packed edge: [31:23]=bucket, [22:16]=dst&127, [15:0]=src
__global__ void k_scat1(const int* __restrict__ src, const int* __restrict__ dst,
                        int* __restrict__ bcur, unsigned* __restrict__ eord) {
    __shared__ int hist[NB];
    __shared__ int gbase[NB];
    const int t = threadIdx.x;
    const int e0 = blockIdx.x * CHUNK;
    for (int j = t; j < NB; j += 256) hist[j] = 0;
    __syncthreads();
    unsigned pk[32];
#pragma unroll
    for (int i = 0; i < 32; ++i) {
        int e = e0 + t + i * 256;
        pk[i] = 0xFFFFFFFFu;
        if (e < NE) {
            unsigned s = (unsigned)src[e];
            unsigned d = (unsigned)dst[e];
            unsigned bk = d >> 7;
            pk[i] = (bk << 23) | ((d & 127u) << 16) | s;
            atomicAdd(&hist[bk], 1);
        }
    }
    __syncthreads();
    for (int j = t; j < NB; j += 256) {
        int c = hist[j];
        gbase[j] = c ? atomicAdd(&bcur[j], c) : 0;
        hist[j] = 0;  // reuse as within-block cursor
    }
    __syncthreads();
#pragma unroll
    for (int i = 0; i < 32; ++i) {
        if (pk[i] != 0xFFFFFFFFu) {
            int bk = pk[i] >> 23;
            int pos = gbase[bk] + atomicAdd(&hist[bk], 1);
            eord[pos] = pk[i];
        }
    }
}

// ---------------- pass 2: within-bucket sort + degrees + row_start + dinv ----------------
__global__ void k_scat2(const int* __restrict__ bbase, const unsigned* __restrict__ eord,
                        unsigned short* __restrict__ esrc16, int* __restrict__ row_start,
                        float* __restrict__ dinv) {
    __shared__ int cnt[128];
    __shared__ int pre[128];
    __shared__ int cur[128];
    const int b = blockIdx.x, t = threadIdx.x, d0 = b << 7;
    if (t < 128) cnt[t] = 0;
    __syncthreads();
    const int beg = bbase[b], end = bbase[b + 1];
    for (int i = beg + t; i < end; i += 256) atomicAdd(&cnt[(eord[i] >> 16) & 127], 1);
    __syncthreads();
    int v = (t < 128) ? cnt[t] : 0;
    if (t < 128) pre[t] = v;
    __syncthreads();
    for (int o = 1; o < 128; o <<= 1) {
        int a = (t < 128 && t >= o) ? pre[t - o] : 0;
        __syncthreads();
        if (t < 128) pre[t] += a;
        __syncthreads();
    }
    if (t < 128) {
        int ex = beg + pre[t] - v;
        int d = d0 + t;
        if (d < NN) {
            row_start[d] = ex;
            dinv[d] = rsqrtf((float)(v + 1));  // +1 self-loop
        }
        cur[t] = ex;
    }
    if (b == NB - 1 && t == 0) row_start[NN] = NE;
    __syncthreads();
    for (int i = beg + t; i < end; i += 256) {
        unsigned x = eord[i];
        int pos = atomicAdd(&cur[(x >> 16) & 127], 1);
        esrc16[pos] = (unsigned short)(x & 0xFFFFu);
    }
}

// ---------------- GEMM1: Hb[N,64 u32] = pack_bf16(dinv[r] * (X[N,128] @ W1[128,128])) ----------------
// 256 thr, 32-row tile; thread = (rg=t>>5: 4 rows) x (cp=t&31: 4 cols)
__global__ void k_gemm1(const float* __restrict__ X, const float* __restrict__ W,
                        const float* __restrict__ dinv, unsigned* __restrict__ Hb) {
    __shared__ float xs[32][128];
    const int t = threadIdx.x;
    const int r0 = blockIdx.x * 32;
    const int cp = t & 31, rg = t >> 5;
    for (int i = 0; i < 4; ++i) {
        int idx = t + i * 256;
        int r = idx >> 5, c4 = idx & 31;
        float4 v = (r0 + r < NN) ? ((const float4*)(X + (size_t)(r0 + r) * 128))[c4]
                                 : make_float4(0.f, 0.f, 0.f, 0.f);
        ((float4*)&xs[r][0])[c4] = v;
    }
    __syncthreads();
    float4 acc[4];
#pragma unroll
    for (int r = 0; r < 4; ++r) acc[r] = make_float4(0.f, 0.f, 0.f, 0.f);
    for (int k0 = 0; k0 < 128; k0 += 4) {
        float4 xr[4];
#pragma unroll
        for (int r = 0; r < 4; ++r) xr[r] = ((const float4*)&xs[rg * 4 + r][0])[k0 >> 2];
#pragma unroll
        for (int kk = 0; kk < 4; ++kk) {
            float4 wv = ((const float4*)(W + (size_t)(k0 + kk) * 128))[cp];
#pragma unroll
            for (int r = 0; r < 4; ++r) {
                float xv = (kk == 0) ? xr[r].x : (kk == 1) ? xr[r].y : (kk == 2) ? xr[r].z : xr[r].w;
                acc[r].x = fmaf(xv, wv.x, acc[r].x);
                acc[r].y = fmaf(xv, wv.y, acc[r].y);
                acc[r].z = fmaf(xv, wv.z, acc[r].z);
                acc[r].w = fmaf(xv, wv.w, acc[r].w);
            }
        }
    }
#pragma unroll
    for (int r = 0; r < 4; ++r) {
        int row = r0 + rg * 4 + r;
        if (row < NN) {
            float s = dinv[row];
            uint2 p;
            p.x = pack_bf16x2(acc[r].x * s, acc[r].y * s);
            p.y = pack_bf16x2(acc[r].z * s, acc[r].w * s);
            ((uint2*)(Hb + (size_t)row * 64))[cp] = p;
        }
    }
}

// ---------------- GEMM2: Hb2[N,32 u32] = pack_bf16(dinv[r] * (X2[N,128] @ W2[128,64])) ----------------
// 256 thr, 64-row tile; thread = (rg=t>>4: 4 rows) x (cp=t&15: 4 cols)
__global__ void k_gemm2(const float* __restrict__ X, const float* __restrict__ W,
                        const float* __restrict__ dinv, unsigned* __restrict__ Hb) {
    __shared__ float xs[64][128];
    const int t = threadIdx.x;
    const int r0 = blockIdx.x * 64;
    const int cp = t & 15, rg = t >> 4;
    for (int i = 0; i < 8; ++i) {
        int idx = t + i * 256;
        int r = idx >> 5, c4 = idx & 31;
        float4 v = (r0 + r < NN) ? ((const float4*)(X + (size_t)(r0 + r) * 128))[c4]
                                 : make_float4(0.f, 0.f, 0.f, 0.f);
        ((float4*)&xs[r][0])[c4] = v;
    }
    __syncthreads();
    float4 acc[4];
#pragma unroll
    for (int r = 0; r < 4; ++r) acc[r] = make_float4(0.f, 0.f, 0.f, 0.f);
    for (int k0 = 0; k0 < 128; k0 += 4) {
        float4 xr[4];
#pragma unroll
        for (int r = 0; r < 4; ++r) xr[r] = ((const float4*)&xs[rg * 4 + r][0])[k0 >> 2];
#pragma unroll
        for (int kk = 0; kk < 4; ++kk) {
            float4 wv = ((const float4*)(W + (size_t)(k0 + kk) * 64))[cp];
#pragma unroll
            for (int r = 0; r < 4; ++r) {
                float xv = (kk == 0) ? xr[r].x : (kk == 1) ? xr[r].y : (kk == 2) ? xr[r].z : xr[r].w;
                acc[r].x = fmaf(xv, wv.x, acc[r].x);
                acc[r].y = fmaf(xv, wv.y, acc[r].y);
                acc[r].z = fmaf(xv, wv.z, acc[r].z);
                acc[r].w = fmaf(xv, wv.w, acc[r].w);
            }
        }
    }
#pragma unroll
    for (int r = 0; r < 4; ++r) {
        int row = r0 + rg * 4 + r;
        if (row < NN) {
            float s = dinv[row];
            uint2 p;
            p.x = pack_bf16x2(acc[r].x * s, acc[r].y * s);
            p.y = pack_bf16x2(acc[r].z * s, acc[r].w * s);
            ((uint2*)(Hb + (size_t)row * 32))[cp] = p;
        }
    }
}

// ---------------- layer-1 aggregate: split-wave, uint2/lane (2 edges in flight/load) ----------------
__global__ void k_agg1(const int* __restrict__ row_start, const unsigned short* __restrict__ esrc,
                       const unsigned* __restrict__ Hb, const float* __restrict__ dinv,
                       const float* __restrict__ b, float* __restrict__ X2) {
    int wid = (blockIdx.x * blockDim.x + threadIdx.x) >> 6;
    int lane = threadIdx.x & 63;
    if (wid >= NN) return;
    int beg = row_start[wid];
    int n = row_start[wid + 1] - beg;
    int half = lane >> 5, l = lane & 31;
    int nh = n >> 1;
    int mb = beg + (half ? nh : 0);
    int mn = half ? (n - nh) : nh;
    const uint2* Hp = (const uint2*)Hb;  // row = 32 uint2
    float a0 = 0.f, a1 = 0.f, a2 = 0.f, a3 = 0.f;
    int j = 0;
    for (; j + 4 <= mn; j += 4) {
        int s0 = esrc[mb + j + 0], s1 = esrc[mb + j + 1];
        int s2 = esrc[mb + j + 2], s3 = esrc[mb + j + 3];
        uint2 v0 = Hp[(size_t)s0 * 32 + l];
        uint2 v1 = Hp[(size_t)s1 * 32 + l];
        uint2 v2 = Hp[(size_t)s2 * 32 + l];
        uint2 v3 = Hp[(size_t)s3 * 32 + l];
        a0 += bf16_lo(v0.x) + bf16_lo(v1.x) + bf16_lo(v2.x) + bf16_lo(v3.x);
        a1 += bf16_hi(v0.x) + bf16_hi(v1.x) + bf16_hi(v2.x) + bf16_hi(v3.x);
        a2 += bf16_lo(v0.y) + bf16_lo(v1.y) + bf16_lo(v2.y) + bf16_lo(v3.y);
        a3 += bf16_hi(v0.y) + bf16_hi(v1.y) + bf16_hi(v2.y) + bf16_hi(v3.y);
    }
    for (; j < mn; ++j) {
        uint2 v = Hp[(size_t)esrc[mb + j] * 32 + l];
        a0 += bf16_lo(v.x); a1 += bf16_hi(v.x);
        a2 += bf16_lo(v.y); a3 += bf16_hi(v.y);
    }
    a0 += __shfl_xor(a0, 32);
    a1 += __shfl_xor(a1, 32);
    a2 += __shfl_xor(a2, 32);
    a3 += __shfl_xor(a3, 32);
    if (half == 0) {
        uint2 vs = Hp[(size_t)wid * 32 + l];  // self-loop
        a0 += bf16_lo(vs.x); a1 += bf16_hi(vs.x);
        a2 += bf16_lo(vs.y); a3 += bf16_hi(vs.y);
        float di = dinv[wid];
        float4 bv = ((const float4*)b)[l];
        float4 o;
        o.x = fmaxf(fmaf(di, a0, bv.x), 0.f);
        o.y = fmaxf(fmaf(di, a1, bv.y), 0.f);
        o.z = fmaxf(fmaf(di, a2, bv.z), 0.f);
        o.w = fmaxf(fmaf(di, a3, bv.w), 0.f);
        ((float4*)X2)[(size_t)wid * 32 + l] = o;
    }
}

// ---------------- layer-2 aggregate + log_softmax: split-wave, u32/lane ----------------
__global__ void k_agg2_lsm(const int* __restrict__ row_start, const unsigned short* __restrict__ esrc,
                           const unsigned* __restrict__ Hb, const float* __restrict__ dinv,
                           const float* __restrict__ b, float* __restrict__ OUT) {
    int wid = (blockIdx.x * blockDim.x + threadIdx.x) >> 6;
    int lane = threadIdx.x & 63;
    if (wid >= NN) return;
    int beg = row_start[wid];
    int n = row_start[wid + 1] - beg;
    int half = lane >> 5, l = lane & 31;
    int nh = n >> 1;
    int mb = beg + (half ? nh : 0);
    int mn = half ? (n - nh) : nh;
    float a0 = 0.f, a1 = 0.f;
    int j = 0;
    for (; j + 4 <= mn; j += 4) {
        int s0 = esrc[mb + j + 0], s1 = esrc[mb + j + 1];
        int s2 = esrc[mb + j + 2], s3 = esrc[mb + j + 3];
        unsigned v0 = Hb[(size_t)s0 * 32 + l];
        unsigned v1 = Hb[(size_t)s1 * 32 + l];
        unsigned v2 = Hb[(size_t)s2 * 32 + l];
        unsigned v3 = Hb[(size_t)s3 * 32 + l];
        a0 += bf16_lo(v0) + bf16_lo(v1) + bf16_lo(v2) + bf16_lo(v3);
        a1 += bf16_hi(v0) + bf16_hi(v1) + bf16_hi(v2) + bf16_hi(v3);
    }
    for (; j < mn; ++j) {
        unsigned v = Hb[(size_t)esrc[mb + j] * 32 + l];
        a0 += bf16_lo(v); a1 += bf16_hi(v);
    }
    a0 += __shfl_xor(a0, 32);
    a1 += __shfl_xor(a1, 32);
    unsigned vs = Hb[(size_t)wid * 32 + l];  // self-loop (both halves compute same)
    a0 += bf16_lo(vs); a1 += bf16_hi(vs);
    float di = dinv[wid];
    float2 bv = ((const float2*)b)[l];
    float v0 = fmaf(di, a0, bv.x);
    float v1 = fmaf(di, a1, bv.y);
    float m = fmaxf(v0, v1);
#pragma unroll
    for (int o = 16; o > 0; o >>= 1) m = fmaxf(m, __shfl_xor(m, o));
    float s = expf(v0 - m) + expf(v1 - m);
#pragma unroll
    for (int o = 16; o > 0; o >>= 1) s += __shfl_xor(s, o);
    float ls = logf(s);
    if (half == 0) {
        float2 o2;
        o2.x = v0 - m - ls;
        o2.y = v1 - m - ls;
        ((float2*)OUT)[(size_t)wid * 32 + l] = o2;
    }
}

extern "C" void kernel_launch(void* const* d_in, const int* in_sizes, int n_in,
                              void* d_out, int out_size, void* d_ws, size_t ws_size,
                              hipStream_t stream) {
    const float* x = (const float*)d_in[0];
    const int* ei = (const int*)d_in[1];  // [2, NE] int32
    const float* W1 = (const float*)d_in[2];
    const float* b1 = (const float*)d_in[3];
    const float* W2 = (const float*)d_in[4];
    const float* b2 = (const float*)d_in[5];
    float* out = (float*)d_out;

    const int* src = ei;
    const int* dst = ei + NE;

    // workspace layout (16B-aligned chunks)
    int* bhist = (int*)d_ws;                                 // NBP
    int* bbase = bhist + NBP;                                // NBP (NB+1 used)
    int* bcur = bbase + NBP;                                 // NBP
    unsigned* eord = (unsigned*)(bcur + NBP);                // NE
    unsigned short* esrc16 = (unsigned short*)(eord + NE);   // NE
    int* row_start = (int*)(esrc16 + NE);                    // 50016 (NN+1 used)
    float* dinv = (float*)(row_start + 50016);               // NN
    unsigned* H1b = (unsigned*)(dinv + NN);                  // NN*64
    unsigned* H2b = H1b + (size_t)NN * 64;                   // NN*32
    float* X2 = (float*)(H2b + (size_t)NN * 32);             // NN*128

    hipMemsetAsync(bhist, 0, NBP * sizeof(int), stream);
    k_hist<<<NCH, 256, 0, stream>>>(dst, bhist);
    k_bscan<<<1, 512, 0, stream>>>(bhist, bbase, bcur);
    k_scat1<<<NCH, 256, 0, stream>>>(src, dst, bcur, eord);
    k_scat2<<<NB, 256, 0, stream>>>(bbase, eord, esrc16, row_start, dinv);

    // layer 1
    k_gemm1<<<(NN + 31) / 32, 256, 0, stream>>>(x, W1, dinv, H1b);
    k_agg1<<<(NN * 64 + 255) / 256, 256, 0, stream>>>(row_start, esrc16, H1b, dinv, b1, X2);
    // layer 2
    k_gemm2<<<(NN + 63) / 64, 256, 0, stream>>>(X2, W2, dinv, H2b);
    k_agg2_lsm<<<(NN * 64 + 255) / 256, 256, 0, stream>>>(row_start, esrc16, H2b, dinv, b2, out);
}

// Round 7
// 172.602 us; speedup vs baseline: 12.4097x; 1.0302x over previous
//
#include <hip/hip_runtime.h>

#define NN 50000
#define NE 800000
#define NB 391            // dst buckets of 128 nodes (391*128 = 50048)
#define NBP 392           // padded row stride for pbh
#define CHUNK 8192        // edges per pass-1 block
#define NCH ((NE + CHUNK - 1) / CHUNK)  // 98 blocks

__device__ __forceinline__ unsigned pack_bf16x2(float a, float b) {
    unsigned ua = __float_as_uint(a);
    unsigned ub = __float_as_uint(b);
    ua = (ua + 0x7FFFu + ((ua >> 16) & 1u)) >> 16;
    ub = (ub + 0x7FFFu + ((ub >> 16) & 1u)) >> 16;
    return ua | (ub << 16);
}
__device__ __forceinline__ float bf16_lo(unsigned u) { return __uint_as_float(u << 16); }
__device__ __forceinline__ float bf16_hi(unsigned u) { return __uint_as_float(u & 0xFFFF0000u); }

// ---------------- per-chunk bucket histogram (no global atomics, no pre-zero) ----------------
__global__ void k_hist(const int* __restrict__ dst, int* __restrict__ pbh) {
    __shared__ int h[NB];
    const int t = threadIdx.x;
    for (int j = t; j < NB; j += 256) h[j] = 0;
    __syncthreads();
    const int e0 = blockIdx.x * CHUNK;
#pragma unroll 8
    for (int i = 0; i < 32; ++i) {
        int e = e0 + t + i * 256;
        if (e < NE) atomicAdd(&h[dst[e] >> 7], 1);
    }
    __syncthreads();
    for (int j = t; j < NB; j += 256) pbh[blockIdx.x * NBP + j] = h[j];
}

// ---------------- bucket totals + exclusive scan + per-chunk bases (1 block of 512) ----------------
__global__ void k_bscan(int* __restrict__ pbh, int* __restrict__ bbase) {
    __shared__ int s[512];
    const int t = threadIdx.x;
    int tot = 0;
    if (t < NB)
        for (int c = 0; c < NCH; ++c) tot += pbh[c * NBP + t];
    s[t] = (t < NB) ? tot : 0;
    __syncthreads();
    for (int o = 1; o < 512; o <<= 1) {
        int a = (t >= o) ? s[t - o] : 0;
        __syncthreads();
        s[t] += a;
        __syncthreads();
    }
    int ex = s[t] - tot;
    if (t < NB) {
        bbase[t] = ex;
        int run = ex;
        for (int c = 0; c < NCH; ++c) {
            int tmp = pbh[c * NBP + t];
            pbh[c * NBP + t] = run;  // becomes this chunk's base for bucket t
            run += tmp;
        }
    }
    if (t == 0) bbase[NB] = NE;
}

// ---------------- pass 1: bucket-bin edges (exact precomputed bases) ----------------
// packed edge: [22:16]=dst&127, [15:0]=src (bucket implicit by segment)
__global__ void k_scat1(const int* __restrict__ src, const int* __restrict__ dst,
                        const int* __restrict__ pbh, unsigned* __restrict__ eord) {
    __shared__ int cur[NB];
    const int t = threadIdx.x;
    const int e0 = blockIdx.x * CHUNK;
    for (int j = t; j < NB; j += 256) cur[j] = pbh[blockIdx.x * NBP + j];
    __syncthreads();
#pragma unroll 8
    for (int i = 0; i < 32; ++i) {
        int e = e0 + t + i * 256;
        if (e < NE) {
            unsigned s = (unsigned)src[e];
            unsigned d = (unsigned)dst[e];
            int pos = atomicAdd(&cur[d >> 7], 1);
            eord[pos] = ((d & 127u) << 16) | s;
        }
    }
}

// ---------------- pass 2: within-bucket sort + row_start + dinv ----------------
__global__ void k_scat2(const int* __restrict__ bbase, const unsigned* __restrict__ eord,
                        unsigned short* __restrict__ esrc16, int* __restrict__ row_start,
                        float* __restrict__ dinv) {
    __shared__ int cnt[128];
    __shared__ int pre[128];
    __shared__ int cur[128];
    const int b = blockIdx.x, t = threadIdx.x, d0 = b << 7;
    if (t < 128) cnt[t] = 0;
    __syncthreads();
    const int beg = bbase[b], end = bbase[b + 1];
    for (int i = beg + t; i < end; i += 256) atomicAdd(&cnt[(eord[i] >> 16) & 127], 1);
    __syncthreads();
    int v = (t < 128) ? cnt[t] : 0;
    if (t < 128) pre[t] = v;
    __syncthreads();
    for (int o = 1; o < 128; o <<= 1) {
        int a = (t < 128 && t >= o) ? pre[t - o] : 0;
        __syncthreads();
        if (t < 128) pre[t] += a;
        __syncthreads();
    }
    if (t < 128) {
        int ex = beg + pre[t] - v;
        int d = d0 + t;
        if (d < NN) {
            row_start[d] = ex;
            dinv[d] = rsqrtf((float)(v + 1));  // +1 self-loop
        }
        cur[t] = ex;
    }
    if (b == NB - 1 && t == 0) row_start[NN] = NE;
    __syncthreads();
    for (int i = beg + t; i < end; i += 256) {
        unsigned x = eord[i];
        int pos = atomicAdd(&cur[(x >> 16) & 127], 1);
        esrc16[pos] = (unsigned short)(x & 0xFFFFu);
    }
}

// ---------------- GEMM1: Hb[N,64 u32] = pack_bf16(dinv[r] * (X[N,128] @ W1[128,128])) ----------------
// W1 staged in LDS (64KB) + 32-row x tile (16KB) = 80KB -> 2 blocks/CU.
// thread = (rg=t>>5: 4 rows) x (cp=t&31: 4 cols); inner loop pure LDS.
__global__ __launch_bounds__(256) void k_gemm1(const float* __restrict__ X,
                                               const float* __restrict__ W,
                                               const float* __restrict__ dinv,
                                               unsigned* __restrict__ Hb) {
    __shared__ float ws[128][128];  // 64KB
    __shared__ float xs[32][128];   // 16KB
    const int t = threadIdx.x;
    const int r0 = blockIdx.x * 32;
    const int cp = t & 31, rg = t >> 5;
#pragma unroll
    for (int i = 0; i < 16; ++i) {
        int idx = t + i * 256;  // float4 index over 4096
        ((float4*)ws)[idx] = ((const float4*)W)[idx];
    }
#pragma unroll
    for (int i = 0; i < 4; ++i) {
        int idx = t + i * 256;
        int r = idx >> 5, c4 = idx & 31;
        float4 v = (r0 + r < NN) ? ((const float4*)(X + (size_t)(r0 + r) * 128))[c4]
                                 : make_float4(0.f, 0.f, 0.f, 0.f);
        ((float4*)&xs[r][0])[c4] = v;
    }
    __syncthreads();
    float4 acc[4];
#pragma unroll
    for (int r = 0; r < 4; ++r) acc[r] = make_float4(0.f, 0.f, 0.f, 0.f);
    for (int k0 = 0; k0 < 128; k0 += 4) {
        float4 xr[4];
#pragma unroll
        for (int r = 0; r < 4; ++r) xr[r] = ((const float4*)&xs[rg * 4 + r][0])[k0 >> 2];
#pragma unroll
        for (int kk = 0; kk < 4; ++kk) {
            float4 wv = ((const float4*)&ws[k0 + kk][0])[cp];
#pragma unroll
            for (int r = 0; r < 4; ++r) {
                float xv = (kk == 0) ? xr[r].x : (kk == 1) ? xr[r].y : (kk == 2) ? xr[r].z : xr[r].w;
                acc[r].x = fmaf(xv, wv.x, acc[r].x);
                acc[r].y = fmaf(xv, wv.y, acc[r].y);
                acc[r].z = fmaf(xv, wv.z, acc[r].z);
                acc[r].w = fmaf(xv, wv.w, acc[r].w);
            }
        }
    }
#pragma unroll
    for (int r = 0; r < 4; ++r) {
        int row = r0 + rg * 4 + r;
        if (row < NN) {
            float s = dinv[row];
            uint2 p;
            p.x = pack_bf16x2(acc[r].x * s, acc[r].y * s);
            p.y = pack_bf16x2(acc[r].z * s, acc[r].w * s);
            ((uint2*)(Hb + (size_t)row * 64))[cp] = p;
        }
    }
}

// ---------------- GEMM2: Hb2[N,32 u32] = pack_bf16(dinv[r] * (X2[N,128] @ W2[128,64])) ----------------
// W2 in LDS (32KB) + 64-row x tile (32KB) = 64KB -> 2 blocks/CU.
// thread = (rg=t>>4: 4 rows) x (cp=t&15: 4 cols)
__global__ __launch_bounds__(256) void k_gemm2(const float* __restrict__ X,
                                               const float* __restrict__ W,
                                               const float* __restrict__ dinv,
                                               unsigned* __restrict__ Hb) {
    __shared__ float ws[128][64];  // 32KB
    __shared__ float xs[64][128];  // 32KB
    const int t = threadIdx.x;
    const int r0 = blockIdx.x * 64;
    const int cp = t & 15, rg = t >> 4;
#pragma unroll
    for (int i = 0; i < 8; ++i) {
        int idx = t + i * 256;  // float4 index over 2048
        ((float4*)ws)[idx] = ((const float4*)W)[idx];
    }
#pragma unroll
    for (int i = 0; i < 8; ++i) {
        int idx = t + i * 256;
        int r = idx >> 5, c4 = idx & 31;
        float4 v = (r0 + r < NN) ? ((const float4*)(X + (size_t)(r0 + r) * 128))[c4]
                                 : make_float4(0.f, 0.f, 0.f, 0.f);
        ((float4*)&xs[r][0])[c4] = v;
    }
    __syncthreads();
    float4 acc[4];
#pragma unroll
    for (int r = 0; r < 4; ++r) acc[r] = make_float4(0.f, 0.f, 0.f, 0.f);
    for (int k0 = 0; k0 < 128; k0 += 4) {
        float4 xr[4];
#pragma unroll
        for (int r = 0; r < 4; ++r) xr[r] = ((const float4*)&xs[rg * 4 + r][0])[k0 >> 2];
#pragma unroll
        for (int kk = 0; kk < 4; ++kk) {
            float4 wv = ((const float4*)&ws[k0 + kk][0])[cp];
#pragma unroll
            for (int r = 0; r < 4; ++r) {
                float xv = (kk == 0) ? xr[r].x : (kk == 1) ? xr[r].y : (kk == 2) ? xr[r].z : xr[r].w;
                acc[r].x = fmaf(xv, wv.x, acc[r].x);
                acc[r].y = fmaf(xv, wv.y, acc[r].y);
                acc[r].z = fmaf(xv, wv.z, acc[r].z);
                acc[r].w = fmaf(xv, wv.w, acc[r].w);
            }
        }
    }
#pragma unroll
    for (int r = 0; r < 4; ++r) {
        int row = r0 + rg * 4 + r;
        if (row < NN) {
            float s = dinv[row];
            uint2 p;
            p.x = pack_bf16x2(acc[r].x * s, acc[r].y * s);
            p.y = pack_bf16x2(acc[r].z * s, acc[r].w * s);
            ((uint2*)(Hb + (size_t)row * 32))[cp] = p;
        }
    }
}

// ---------------- layer-1 aggregate: split-wave, uint2/lane (2 edges in flight/load) ----------------
__global__ void k_agg1(const int* __restrict__ row_start, const unsigned short* __restrict__ esrc,
                       const unsigned* __restrict__ Hb, const float* __restrict__ dinv,
                       const float* __restrict__ b, float* __restrict__ X2) {
    int wid = (blockIdx.x * blockDim.x + threadIdx.x) >> 6;
    int lane = threadIdx.x & 63;
    if (wid >= NN) return;
    int beg = row_start[wid];
    int n = row_start[wid + 1] - beg;
    int half = lane >> 5, l = lane & 31;
    int nh = n >> 1;
    int mb = beg + (half ? nh : 0);
    int mn = half ? (n - nh) : nh;
    const uint2* Hp = (const uint2*)Hb;  // row = 32 uint2
    float a0 = 0.f, a1 = 0.f, a2 = 0.f, a3 = 0.f;
    int j = 0;
    for (; j + 4 <= mn; j += 4) {
        int s0 = esrc[mb + j + 0], s1 = esrc[mb + j + 1];
        int s2 = esrc[mb + j + 2], s3 = esrc[mb + j + 3];
        uint2 v0 = Hp[(size_t)s0 * 32 + l];
        uint2 v1 = Hp[(size_t)s1 * 32 + l];
        uint2 v2 = Hp[(size_t)s2 * 32 + l];
        uint2 v3 = Hp[(size_t)s3 * 32 + l];
        a0 += bf16_lo(v0.x) + bf16_lo(v1.x) + bf16_lo(v2.x) + bf16_lo(v3.x);
        a1 += bf16_hi(v0.x) + bf16_hi(v1.x) + bf16_hi(v2.x) + bf16_hi(v3.x);
        a2 += bf16_lo(v0.y) + bf16_lo(v1.y) + bf16_lo(v2.y) + bf16_lo(v3.y);
        a3 += bf16_hi(v0.y) + bf16_hi(v1.y) + bf16_hi(v2.y) + bf16_hi(v3.y);
    }
    for (; j < mn; ++j) {
        uint2 v = Hp[(size_t)esrc[mb + j] * 32 + l];
        a0 += bf16_lo(v.x); a1 += bf16_hi(v.x);
        a2 += bf16_lo(v.y); a3 += bf16_hi(v.y);
    }
    a0 += __shfl_xor(a0, 32);
    a1 += __shfl_xor(a1, 32);
    a2 += __shfl_xor(a2, 32);
    a3 += __shfl_xor(a3, 32);
    if (half == 0) {
        uint2 vs = Hp[(size_t)wid * 32 + l];  // self-loop
        a0 += bf16_lo(vs.x); a1 += bf16_hi(vs.x);
        a2 += bf16_lo(vs.y); a3 += bf16_hi(vs.y);
        float di = dinv[wid];
        float4 bv = ((const float4*)b)[l];
        float4 o;
        o.x = fmaxf(fmaf(di, a0, bv.x), 0.f);
        o.y = fmaxf(fmaf(di, a1, bv.y), 0.f);
        o.z = fmaxf(fmaf(di, a2, bv.z), 0.f);
        o.w = fmaxf(fmaf(di, a3, bv.w), 0.f);
        ((float4*)X2)[(size_t)wid * 32 + l] = o;
    }
}

// ---------------- layer-2 aggregate + log_softmax: split-wave, u32/lane ----------------
__global__ void k_agg2_lsm(const int* __restrict__ row_start, const unsigned short* __restrict__ esrc,
                           const unsigned* __restrict__ Hb, const float* __restrict__ dinv,
                           const float* __restrict__ b, float* __restrict__ OUT) {
    int wid = (blockIdx.x * blockDim.x + threadIdx.x) >> 6;
    int lane = threadIdx.x & 63;
    if (wid >= NN) return;
    int beg = row_start[wid];
    int n = row_start[wid + 1] - beg;
    int half = lane >> 5, l = lane & 31;
    int nh = n >> 1;
    int mb = beg + (half ? nh : 0);
    int mn = half ? (n - nh) : nh;
    float a0 = 0.f, a1 = 0.f;
    int j = 0;
    for (; j + 4 <= mn; j += 4) {
        int s0 = esrc[mb + j + 0], s1 = esrc[mb + j + 1];
        int s2 = esrc[mb + j + 2], s3 = esrc[mb + j + 3];
        unsigned v0 = Hb[(size_t)s0 * 32 + l];
        unsigned v1 = Hb[(size_t)s1 * 32 + l];
        unsigned v2 = Hb[(size_t)s2 * 32 + l];
        unsigned v3 = Hb[(size_t)s3 * 32 + l];
        a0 += bf16_lo(v0) + bf16_lo(v1) + bf16_lo(v2) + bf16_lo(v3);
        a1 += bf16_hi(v0) + bf16_hi(v1) + bf16_hi(v2) + bf16_hi(v3);
    }
    for (; j < mn; ++j) {
        unsigned v = Hb[(size_t)esrc[mb + j] * 32 + l];
        a0 += bf16_lo(v); a1 += bf16_hi(v);
    }
    a0 += __shfl_xor(a0, 32);
    a1 += __shfl_xor(a1, 32);
    unsigned vs = Hb[(size_t)wid * 32 + l];  // self-loop (both halves compute same)
    a0 += bf16_lo(vs); a1 += bf16_hi(vs);
    float di = dinv[wid];
    float2 bv = ((const float2*)b)[l];
    float v0 = fmaf(di, a0, bv.x);
    float v1 = fmaf(di, a1, bv.y);
    float m = fmaxf(v0, v1);
#pragma unroll
    for (int o = 16; o > 0; o >>= 1) m = fmaxf(m, __shfl_xor(m, o));
    float s = expf(v0 - m) + expf(v1 - m);
#pragma unroll
    for (int o = 16; o > 0; o >>= 1) s += __shfl_xor(s, o);
    float ls = logf(s);
    if (half == 0) {
        float2 o2;
        o2.x = v0 - m - ls;
        o2.y = v1 - m - ls;
        ((float2*)OUT)[(size_t)wid * 32 + l] = o2;
    }
}

extern "C" void kernel_launch(void* const* d_in, const int* in_sizes, int n_in,
                              void* d_out, int out_size, void* d_ws, size_t ws_size,
                              hipStream_t stream) {
    const float* x = (const float*)d_in[0];
    const int* ei = (const int*)d_in[1];  // [2, NE] int32
    const float* W1 = (const float*)d_in[2];
    const float* b1 = (const float*)d_in[3];
    const float* W2 = (const float*)d_in[4];
    const float* b2 = (const float*)d_in[5];
    float* out = (float*)d_out;

    const int* src = ei;
    const int* dst = ei + NE;

    // workspace layout (16B-aligned chunks)
    int* bbase = (int*)d_ws;                                 // 400 (NB+1 used)
    int* pbh = bbase + 400;                                  // NCH*NBP
    unsigned* eord = (unsigned*)(pbh + NCH * NBP);           // NE
    unsigned short* esrc16 = (unsigned short*)(eord + NE);   // NE
    int* row_start = (int*)(esrc16 + NE);                    // 50016 (NN+1 used)
    float* dinv = (float*)(row_start + 50016);               // NN
    unsigned* H1b = (unsigned*)(dinv + NN);                  // NN*64
    unsigned* H2b = H1b + (size_t)NN * 64;                   // NN*32
    float* X2 = (float*)(H2b + (size_t)NN * 32);             // NN*128

    k_hist<<<NCH, 256, 0, stream>>>(dst, pbh);
    k_bscan<<<1, 512, 0, stream>>>(pbh, bbase);
    k_scat1<<<NCH, 256, 0, stream>>>(src, dst, pbh, eord);
    k_scat2<<<NB, 256, 0, stream>>>(bbase, eord, esrc16, row_start, dinv);

    // layer 1
    k_gemm1<<<(NN + 31) / 32, 256, 0, stream>>>(x, W1, dinv, H1b);
    k_agg1<<<(NN * 64 + 255) / 256, 256, 0, stream>>>(row_start, esrc16, H1b, dinv, b1, X2);
    // layer 2
    k_gemm2<<<(NN + 63) / 64, 256, 0, stream>>>(X2, W2, dinv, H2b);
    k_agg2_lsm<<<(NN * 64 + 255) / 256, 256, 0, stream>>>(row_start, esrc16, H2b, dinv, b2, out);
}

// Round 8
// 146.002 us; speedup vs baseline: 14.6706x; 1.1822x over previous
//
#include <hip/hip_runtime.h>

#define NN 50000
#define NE 800000
#define NB 391            // dst buckets of 128 nodes (391*128 = 50048)
#define NBP 392           // padded row stride for pbh
#define CHUNK 8192        // edges per pass-1 block
#define NCH ((NE + CHUNK - 1) / CHUNK)  // 98 blocks

typedef __attribute__((ext_vector_type(8))) short bf16x8;
typedef __attribute__((ext_vector_type(4))) float f32x4;

__device__ __forceinline__ unsigned pack_bf16x2(float a, float b) {
    unsigned ua = __float_as_uint(a);
    unsigned ub = __float_as_uint(b);
    ua = (ua + 0x7FFFu + ((ua >> 16) & 1u)) >> 16;
    ub = (ub + 0x7FFFu + ((ub >> 16) & 1u)) >> 16;
    return ua | (ub << 16);
}
__device__ __forceinline__ float bf16_lo(unsigned u) { return __uint_as_float(u << 16); }
__device__ __forceinline__ float bf16_hi(unsigned u) { return __uint_as_float(u & 0xFFFF0000u); }

// ---------------- X -> bf16 row-major (MFMA B-fragment-ready) ----------------
__global__ void k_xconv(const float* __restrict__ X, unsigned short* __restrict__ Xb) {
    int i = blockIdx.x * blockDim.x + threadIdx.x;  // one per 8 elems
    if (i >= NN * 128 / 8) return;
    const float4* p = (const float4*)X + (size_t)i * 2;
    float4 a = p[0], b = p[1];
    uint4 o;
    o.x = pack_bf16x2(a.x, a.y);
    o.y = pack_bf16x2(a.z, a.w);
    o.z = pack_bf16x2(b.x, b.y);
    o.w = pack_bf16x2(b.z, b.w);
    ((uint4*)Xb)[i] = o;
}

// ---------------- pack W[128][M] -> Wpk[(ct*4+t)*64+l][8] bf16 (A-fragment order) ----------------
template <int M>
__global__ void k_wpack(const float* __restrict__ W, unsigned short* __restrict__ Wpk) {
    int idx = blockIdx.x * blockDim.x + threadIdx.x;  // (ct*4 + t)*64 + l
    if (idx >= (M / 16) * 4 * 64) return;
    int l = idx & 63;
    int t = (idx >> 6) & 3;
    int ct = idx >> 8;
    int col = ct * 16 + (l & 15);
    int k0 = t * 32 + (l >> 4) * 8;
    unsigned* o = (unsigned*)(Wpk + (size_t)idx * 8);
#pragma unroll
    for (int j = 0; j < 8; j += 2)
        o[j >> 1] = pack_bf16x2(W[(size_t)(k0 + j) * M + col], W[(size_t)(k0 + j + 1) * M + col]);
}

// ---------------- per-chunk bucket histogram ----------------
__global__ void k_hist(const int* __restrict__ dst, int* __restrict__ pbh) {
    __shared__ int h[NB];
    const int t = threadIdx.x;
    for (int j = t; j < NB; j += 256) h[j] = 0;
    __syncthreads();
    const int e0 = blockIdx.x * CHUNK;
#pragma unroll 8
    for (int i = 0; i < 32; ++i) {
        int e = e0 + t + i * 256;
        if (e < NE) atomicAdd(&h[dst[e] >> 7], 1);
    }
    __syncthreads();
    for (int j = t; j < NB; j += 256) pbh[blockIdx.x * NBP + j] = h[j];
}

// ---------------- bucket totals + exclusive scan + per-chunk bases ----------------
__global__ void k_bscan(int* __restrict__ pbh, int* __restrict__ bbase) {
    __shared__ int s[512];
    const int t = threadIdx.x;
    int tot = 0;
    if (t < NB)
        for (int c = 0; c < NCH; ++c) tot += pbh[c * NBP + t];
    s[t] = (t < NB) ? tot : 0;
    __syncthreads();
    for (int o = 1; o < 512; o <<= 1) {
        int a = (t >= o) ? s[t - o] : 0;
        __syncthreads();
        s[t] += a;
        __syncthreads();
    }
    int ex = s[t] - tot;
    if (t < NB) {
        bbase[t] = ex;
        int run = ex;
        for (int c = 0; c < NCH; ++c) {
            int tmp = pbh[c * NBP + t];
            pbh[c * NBP + t] = run;
            run += tmp;
        }
    }
    if (t == 0) bbase[NB] = NE;
}

// ---------------- pass 1: bucket-bin edges ----------------
__global__ void k_scat1(const int* __restrict__ src, const int* __restrict__ dst,
                        const int* __restrict__ pbh, unsigned* __restrict__ eord) {
    __shared__ int cur[NB];
    const int t = threadIdx.x;
    const int e0 = blockIdx.x * CHUNK;
    for (int j = t; j < NB; j += 256) cur[j] = pbh[blockIdx.x * NBP + j];
    __syncthreads();
#pragma unroll 8
    for (int i = 0; i < 32; ++i) {
        int e = e0 + t + i * 256;
        if (e < NE) {
            unsigned s = (unsigned)src[e];
            unsigned d = (unsigned)dst[e];
            int pos = atomicAdd(&cur[d >> 7], 1);
            eord[pos] = ((d & 127u) << 16) | s;
        }
    }
}

// ---------------- pass 2: within-bucket sort + row_start + dinv ----------------
__global__ void k_scat2(const int* __restrict__ bbase, const unsigned* __restrict__ eord,
                        unsigned short* __restrict__ esrc16, int* __restrict__ row_start,
                        float* __restrict__ dinv) {
    __shared__ int cnt[128];
    __shared__ int pre[128];
    __shared__ int cur[128];
    const int b = blockIdx.x, t = threadIdx.x, d0 = b << 7;
    if (t < 128) cnt[t] = 0;
    __syncthreads();
    const int beg = bbase[b], end = bbase[b + 1];
    for (int i = beg + t; i < end; i += 256) atomicAdd(&cnt[(eord[i] >> 16) & 127], 1);
    __syncthreads();
    int v = (t < 128) ? cnt[t] : 0;
    if (t < 128) pre[t] = v;
    __syncthreads();
    for (int o = 1; o < 128; o <<= 1) {
        int a = (t < 128 && t >= o) ? pre[t - o] : 0;
        __syncthreads();
        if (t < 128) pre[t] += a;
        __syncthreads();
    }
    if (t < 128) {
        int ex = beg + pre[t] - v;
        int d = d0 + t;
        if (d < NN) {
            row_start[d] = ex;
            dinv[d] = rsqrtf((float)(v + 1));  // +1 self-loop
        }
        cur[t] = ex;
    }
    if (b == NB - 1 && t == 0) row_start[NN] = NE;
    __syncthreads();
    for (int i = beg + t; i < end; i += 256) {
        unsigned x = eord[i];
        int pos = atomicAdd(&cur[(x >> 16) & 127], 1);
        esrc16[pos] = (unsigned short)(x & 0xFFFFu);
    }
}

// ---------------- MFMA GEMM1: Hb[N,64 u32] = pack_bf16(dinv * (X @ W1)), no LDS ----------------
// 4 waves/block, wave = 16 rows x 128 cols. mfma(w_frag, x_frag): lane l holds
// row r0+(l&15), cols ct*16 + (l>>4)*4 + q  -> uint2 store matches agg layout.
__global__ __launch_bounds__(256) void k_gemm1(const unsigned short* __restrict__ Xb,
                                               const unsigned short* __restrict__ Wpk,
                                               const float* __restrict__ dinv,
                                               unsigned* __restrict__ Hb) {
    const int t = threadIdx.x;
    const int w = t >> 6, l = t & 63;
    const int row = blockIdx.x * 64 + w * 16 + (l & 15);
    const int rc = row < NN ? row : NN - 1;
    const int lq = l >> 4;
    f32x4 acc[8];
#pragma unroll
    for (int c = 0; c < 8; ++c) acc[c] = (f32x4){0.f, 0.f, 0.f, 0.f};
#pragma unroll
    for (int tt = 0; tt < 4; ++tt) {
        bf16x8 xf = *(const bf16x8*)(Xb + (size_t)rc * 128 + tt * 32 + lq * 8);
#pragma unroll
        for (int c = 0; c < 8; ++c) {
            bf16x8 wf = *(const bf16x8*)(Wpk + (size_t)((c * 4 + tt) * 64 + l) * 8);
            acc[c] = __builtin_amdgcn_mfma_f32_16x16x32_bf16(wf, xf, acc[c], 0, 0, 0);
        }
    }
    if (row < NN) {
        float s = dinv[row];
        uint2* orow = (uint2*)(Hb + (size_t)row * 64);
#pragma unroll
        for (int c = 0; c < 8; ++c) {
            uint2 p;
            p.x = pack_bf16x2(acc[c][0] * s, acc[c][1] * s);
            p.y = pack_bf16x2(acc[c][2] * s, acc[c][3] * s);
            orow[c * 4 + lq] = p;
        }
    }
}

// ---------------- MFMA GEMM2: Hb2[N,32 u32] = pack_bf16(dinv * (X2 @ W2)) ----------------
__global__ __launch_bounds__(256) void k_gemm2(const unsigned short* __restrict__ Xb,
                                               const unsigned short* __restrict__ Wpk,
                                               const float* __restrict__ dinv,
                                               unsigned* __restrict__ Hb) {
    const int t = threadIdx.x;
    const int w = t >> 6, l = t & 63;
    const int row = blockIdx.x * 64 + w * 16 + (l & 15);
    const int rc = row < NN ? row : NN - 1;
    const int lq = l >> 4;
    f32x4 acc[4];
#pragma unroll
    for (int c = 0; c < 4; ++c) acc[c] = (f32x4){0.f, 0.f, 0.f, 0.f};
#pragma unroll
    for (int tt = 0; tt < 4; ++tt) {
        bf16x8 xf = *(const bf16x8*)(Xb + (size_t)rc * 128 + tt * 32 + lq * 8);
#pragma unroll
        for (int c = 0; c < 4; ++c) {
            bf16x8 wf = *(const bf16x8*)(Wpk + (size_t)((c * 4 + tt) * 64 + l) * 8);
            acc[c] = __builtin_amdgcn_mfma_f32_16x16x32_bf16(wf, xf, acc[c], 0, 0, 0);
        }
    }
    if (row < NN) {
        float s = dinv[row];
        uint2* orow = (uint2*)(Hb + (size_t)row * 32);
#pragma unroll
        for (int c = 0; c < 4; ++c) {
            uint2 p;
            p.x = pack_bf16x2(acc[c][0] * s, acc[c][1] * s);
            p.y = pack_bf16x2(acc[c][2] * s, acc[c][3] * s);
            orow[c * 4 + lq] = p;
        }
    }
}

// ---------------- layer-1 aggregate: split-wave, uint2/lane; bf16 output ----------------
__global__ void k_agg1(const int* __restrict__ row_start, const unsigned short* __restrict__ esrc,
                       const unsigned* __restrict__ Hb, const float* __restrict__ dinv,
                       const float* __restrict__ b, unsigned* __restrict__ X2b) {
    int wid = (blockIdx.x * blockDim.x + threadIdx.x) >> 6;
    int lane = threadIdx.x & 63;
    if (wid >= NN) return;
    int beg = row_start[wid];
    int n = row_start[wid + 1] - beg;
    int half = lane >> 5, l = lane & 31;
    int nh = n >> 1;
    int mb = beg + (half ? nh : 0);
    int mn = half ? (n - nh) : nh;
    const uint2* Hp = (const uint2*)Hb;  // row = 32 uint2
    float a0 = 0.f, a1 = 0.f, a2 = 0.f, a3 = 0.f;
    int j = 0;
    for (; j + 4 <= mn; j += 4) {
        int s0 = esrc[mb + j + 0], s1 = esrc[mb + j + 1];
        int s2 = esrc[mb + j + 2], s3 = esrc[mb + j + 3];
        uint2 v0 = Hp[(size_t)s0 * 32 + l];
        uint2 v1 = Hp[(size_t)s1 * 32 + l];
        uint2 v2 = Hp[(size_t)s2 * 32 + l];
        uint2 v3 = Hp[(size_t)s3 * 32 + l];
        a0 += bf16_lo(v0.x) + bf16_lo(v1.x) + bf16_lo(v2.x) + bf16_lo(v3.x);
        a1 += bf16_hi(v0.x) + bf16_hi(v1.x) + bf16_hi(v2.x) + bf16_hi(v3.x);
        a2 += bf16_lo(v0.y) + bf16_lo(v1.y) + bf16_lo(v2.y) + bf16_lo(v3.y);
        a3 += bf16_hi(v0.y) + bf16_hi(v1.y) + bf16_hi(v2.y) + bf16_hi(v3.y);
    }
    for (; j < mn; ++j) {
        uint2 v = Hp[(size_t)esrc[mb + j] * 32 + l];
        a0 += bf16_lo(v.x); a1 += bf16_hi(v.x);
        a2 += bf16_lo(v.y); a3 += bf16_hi(v.y);
    }
    a0 += __shfl_xor(a0, 32);
    a1 += __shfl_xor(a1, 32);
    a2 += __shfl_xor(a2, 32);
    a3 += __shfl_xor(a3, 32);
    if (half == 0) {
        uint2 vs = Hp[(size_t)wid * 32 + l];  // self-loop
        a0 += bf16_lo(vs.x); a1 += bf16_hi(vs.x);
        a2 += bf16_lo(vs.y); a3 += bf16_hi(vs.y);
        float di = dinv[wid];
        float4 bv = ((const float4*)b)[l];
        uint2 st;
        st.x = pack_bf16x2(fmaxf(fmaf(di, a0, bv.x), 0.f), fmaxf(fmaf(di, a1, bv.y), 0.f));
        st.y = pack_bf16x2(fmaxf(fmaf(di, a2, bv.z), 0.f), fmaxf(fmaf(di, a3, bv.w), 0.f));
        ((uint2*)X2b)[(size_t)wid * 32 + l] = st;
    }
}

// ---------------- layer-2 aggregate + log_softmax: split-wave, u32/lane ----------------
__global__ void k_agg2_lsm(const int* __restrict__ row_start, const unsigned short* __restrict__ esrc,
                           const unsigned* __restrict__ Hb, const float* __restrict__ dinv,
                           const float* __restrict__ b, float* __restrict__ OUT) {
    int wid = (blockIdx.x * blockDim.x + threadIdx.x) >> 6;
    int lane = threadIdx.x & 63;
    if (wid >= NN) return;
    int beg = row_start[wid];
    int n = row_start[wid + 1] - beg;
    int half = lane >> 5, l = lane & 31;
    int nh = n >> 1;
    int mb = beg + (half ? nh : 0);
    int mn = half ? (n - nh) : nh;
    float a0 = 0.f, a1 = 0.f;
    int j = 0;
    for (; j + 4 <= mn; j += 4) {
        int s0 = esrc[mb + j + 0], s1 = esrc[mb + j + 1];
        int s2 = esrc[mb + j + 2], s3 = esrc[mb + j + 3];
        unsigned v0 = Hb[(size_t)s0 * 32 + l];
        unsigned v1 = Hb[(size_t)s1 * 32 + l];
        unsigned v2 = Hb[(size_t)s2 * 32 + l];
        unsigned v3 = Hb[(size_t)s3 * 32 + l];
        a0 += bf16_lo(v0) + bf16_lo(v1) + bf16_lo(v2) + bf16_lo(v3);
        a1 += bf16_hi(v0) + bf16_hi(v1) + bf16_hi(v2) + bf16_hi(v3);
    }
    for (; j < mn; ++j) {
        unsigned v = Hb[(size_t)esrc[mb + j] * 32 + l];
        a0 += bf16_lo(v); a1 += bf16_hi(v);
    }
    a0 += __shfl_xor(a0, 32);
    a1 += __shfl_xor(a1, 32);
    unsigned vs = Hb[(size_t)wid * 32 + l];  // self-loop
    a0 += bf16_lo(vs); a1 += bf16_hi(vs);
    float di = dinv[wid];
    float2 bv = ((const float2*)b)[l];
    float v0 = fmaf(di, a0, bv.x);
    float v1 = fmaf(di, a1, bv.y);
    float m = fmaxf(v0, v1);
#pragma unroll
    for (int o = 16; o > 0; o >>= 1) m = fmaxf(m, __shfl_xor(m, o));
    float s = expf(v0 - m) + expf(v1 - m);
#pragma unroll
    for (int o = 16; o > 0; o >>= 1) s += __shfl_xor(s, o);
    float ls = logf(s);
    if (half == 0) {
        float2 o2;
        o2.x = v0 - m - ls;
        o2.y = v1 - m - ls;
        ((float2*)OUT)[(size_t)wid * 32 + l] = o2;
    }
}

extern "C" void kernel_launch(void* const* d_in, const int* in_sizes, int n_in,
                              void* d_out, int out_size, void* d_ws, size_t ws_size,
                              hipStream_t stream) {
    const float* x = (const float*)d_in[0];
    const int* ei = (const int*)d_in[1];  // [2, NE] int32
    const float* W1 = (const float*)d_in[2];
    const float* b1 = (const float*)d_in[3];
    const float* W2 = (const float*)d_in[4];
    const float* b2 = (const float*)d_in[5];
    float* out = (float*)d_out;

    const int* src = ei;
    const int* dst = ei + NE;

    // workspace layout (all segments 16B-aligned)
    int* bbase = (int*)d_ws;                                 // 400
    int* pbh = bbase + 400;                                  // NCH*NBP
    unsigned* eord = (unsigned*)(pbh + NCH * NBP);           // NE
    unsigned short* esrc16 = (unsigned short*)(eord + NE);   // NE
    int* row_start = (int*)(esrc16 + NE);                    // 50016
    float* dinv = (float*)(row_start + 50016);               // NN
    unsigned short* Xb = (unsigned short*)(dinv + NN);       // NN*128 bf16
    unsigned short* Wpk1 = Xb + (size_t)NN * 128;            // 2048*8 bf16 (32KB)
    unsigned short* Wpk2 = Wpk1 + 2048 * 8;                  // 1024*8 bf16 (16KB)
    unsigned* H1b = (unsigned*)(Wpk2 + 1024 * 8);            // NN*64 u32
    unsigned* H2b = H1b + (size_t)NN * 64;                   // NN*32 u32
    unsigned* X2b = H2b + (size_t)NN * 32;                   // NN*64 u32 (bf16x2)

    k_xconv<<<(NN * 128 / 8 + 255) / 256, 256, 0, stream>>>(x, Xb);
    k_wpack<128><<<8, 256, 0, stream>>>(W1, Wpk1);
    k_wpack<64><<<4, 256, 0, stream>>>(W2, Wpk2);
    k_hist<<<NCH, 256, 0, stream>>>(dst, pbh);
    k_bscan<<<1, 512, 0, stream>>>(pbh, bbase);
    k_scat1<<<NCH, 256, 0, stream>>>(src, dst, pbh, eord);
    k_scat2<<<NB, 256, 0, stream>>>(bbase, eord, esrc16, row_start, dinv);

    // layer 1
    k_gemm1<<<(NN + 63) / 64, 256, 0, stream>>>(Xb, Wpk1, dinv, H1b);
    k_agg1<<<(NN * 64 + 255) / 256, 256, 0, stream>>>(row_start, esrc16, H1b, dinv, b1, (unsigned*)X2b);
    // layer 2
    k_gemm2<<<(NN + 63) / 64, 256, 0, stream>>>((const unsigned short*)X2b, Wpk2, dinv, H2b);
    k_agg2_lsm<<<(NN * 64 + 255) / 256, 256, 0, stream>>>(row_start, esrc16, H2b, dinv, b2, out);
}

// Round 9
// 141.754 us; speedup vs baseline: 15.1103x; 1.0300x over previous
//
#include <hip/hip_runtime.h>

#define NN 50000
#define NE 800000
#define NB 391            // dst buckets of 128 nodes (391*128 = 50048)
#define NBP 392           // padded row stride for pbh
#define CHUNK 8192        // edges per pass-1 block
#define NCH ((NE + CHUNK - 1) / CHUNK)  // 98 blocks

typedef __attribute__((ext_vector_type(8))) short bf16x8;
typedef __attribute__((ext_vector_type(4))) float f32x4;

__device__ __forceinline__ unsigned pack_bf16x2(float a, float b) {
    unsigned ua = __float_as_uint(a);
    unsigned ub = __float_as_uint(b);
    ua = (ua + 0x7FFFu + ((ua >> 16) & 1u)) >> 16;
    ub = (ub + 0x7FFFu + ((ub >> 16) & 1u)) >> 16;
    return ua | (ub << 16);
}
__device__ __forceinline__ float bf16_lo(unsigned u) { return __uint_as_float(u << 16); }
__device__ __forceinline__ float bf16_hi(unsigned u) { return __uint_as_float(u & 0xFFFF0000u); }

// ---------------- pack W1[128][128] and W2[128][64] -> MFMA A-fragment order ----------------
__global__ void k_wpack(const float* __restrict__ W1, const float* __restrict__ W2,
                        unsigned short* __restrict__ Wpk1, unsigned short* __restrict__ Wpk2) {
    int gid = blockIdx.x * blockDim.x + threadIdx.x;
    const float* W;
    unsigned short* Wpk;
    int idx, M;
    if (gid < 2048) { W = W1; Wpk = Wpk1; idx = gid; M = 128; }
    else if (gid < 3072) { W = W2; Wpk = Wpk2; idx = gid - 2048; M = 64; }
    else return;
    int l = idx & 63;
    int t = (idx >> 6) & 3;
    int ct = idx >> 8;
    int col = ct * 16 + (l & 15);
    int k0 = t * 32 + (l >> 4) * 8;
    unsigned* o = (unsigned*)(Wpk + (size_t)idx * 8);
#pragma unroll
    for (int j = 0; j < 8; j += 2)
        o[j >> 1] = pack_bf16x2(W[(size_t)(k0 + j) * M + col], W[(size_t)(k0 + j + 1) * M + col]);
}

// ---------------- per-chunk bucket histogram ----------------
__global__ void k_hist(const int* __restrict__ dst, int* __restrict__ pbh) {
    __shared__ int h[NB];
    const int t = threadIdx.x;
    for (int j = t; j < NB; j += 256) h[j] = 0;
    __syncthreads();
    const int e0 = blockIdx.x * CHUNK;
#pragma unroll 8
    for (int i = 0; i < 32; ++i) {
        int e = e0 + t + i * 256;
        if (e < NE) atomicAdd(&h[dst[e] >> 7], 1);
    }
    __syncthreads();
    for (int j = t; j < NB; j += 256) pbh[blockIdx.x * NBP + j] = h[j];
}

// ---------------- bucket totals + exclusive scan + per-chunk bases ----------------
__global__ void k_bscan(int* __restrict__ pbh, int* __restrict__ bbase) {
    __shared__ int s[512];
    const int t = threadIdx.x;
    int tot = 0;
    if (t < NB)
        for (int c = 0; c < NCH; ++c) tot += pbh[c * NBP + t];
    s[t] = (t < NB) ? tot : 0;
    __syncthreads();
    for (int o = 1; o < 512; o <<= 1) {
        int a = (t >= o) ? s[t - o] : 0;
        __syncthreads();
        s[t] += a;
        __syncthreads();
    }
    int ex = s[t] - tot;
    if (t < NB) {
        bbase[t] = ex;
        int run = ex;
        for (int c = 0; c < NCH; ++c) {
            int tmp = pbh[c * NBP + t];
            pbh[c * NBP + t] = run;
            run += tmp;
        }
    }
    if (t == 0) bbase[NB] = NE;
}

// ---------------- pass 1: bucket-bin edges ----------------
__global__ void k_scat1(const int* __restrict__ src, const int* __restrict__ dst,
                        const int* __restrict__ pbh, unsigned* __restrict__ eord) {
    __shared__ int cur[NB];
    const int t = threadIdx.x;
    const int e0 = blockIdx.x * CHUNK;
    for (int j = t; j < NB; j += 256) cur[j] = pbh[blockIdx.x * NBP + j];
    __syncthreads();
#pragma unroll 8
    for (int i = 0; i < 32; ++i) {
        int e = e0 + t + i * 256;
        if (e < NE) {
            unsigned s = (unsigned)src[e];
            unsigned d = (unsigned)dst[e];
            int pos = atomicAdd(&cur[d >> 7], 1);
            eord[pos] = ((d & 127u) << 16) | s;
        }
    }
}

// ---------------- pass 2: within-bucket sort + row_start + dinv ----------------
__global__ void k_scat2(const int* __restrict__ bbase, const unsigned* __restrict__ eord,
                        unsigned short* __restrict__ esrc16, int* __restrict__ row_start,
                        float* __restrict__ dinv) {
    __shared__ int cnt[128];
    __shared__ int pre[128];
    __shared__ int cur[128];
    const int b = blockIdx.x, t = threadIdx.x, d0 = b << 7;
    if (t < 128) cnt[t] = 0;
    __syncthreads();
    const int beg = bbase[b], end = bbase[b + 1];
    for (int i = beg + t; i < end; i += 256) atomicAdd(&cnt[(eord[i] >> 16) & 127], 1);
    __syncthreads();
    int v = (t < 128) ? cnt[t] : 0;
    if (t < 128) pre[t] = v;
    __syncthreads();
    for (int o = 1; o < 128; o <<= 1) {
        int a = (t < 128 && t >= o) ? pre[t - o] : 0;
        __syncthreads();
        if (t < 128) pre[t] += a;
        __syncthreads();
    }
    if (t < 128) {
        int ex = beg + pre[t] - v;
        int d = d0 + t;
        if (d < NN) {
            row_start[d] = ex;
            dinv[d] = rsqrtf((float)(v + 1));  // +1 self-loop
        }
        cur[t] = ex;
    }
    if (b == NB - 1 && t == 0) row_start[NN] = NE;
    __syncthreads();
    for (int i = beg + t; i < end; i += 256) {
        unsigned x = eord[i];
        int pos = atomicAdd(&cur[(x >> 16) & 127], 1);
        esrc16[pos] = (unsigned short)(x & 0xFFFFu);
    }
}

// ---------------- MFMA GEMM1 (reads f32 X directly, packs fragments in-register) ----------------
// 4 waves/block, wave = 16 rows x 128 cols. mfma(w_frag, x_frag): lane l holds
// row r0+(l&15), cols ct*16 + (l>>4)*4 + q  -> uint2 store matches agg layout.
__global__ __launch_bounds__(256) void k_gemm1(const float* __restrict__ X,
                                               const unsigned short* __restrict__ Wpk,
                                               const float* __restrict__ dinv,
                                               unsigned* __restrict__ Hb) {
    const int t = threadIdx.x;
    const int w = t >> 6, l = t & 63;
    const int row = blockIdx.x * 64 + w * 16 + (l & 15);
    const int rc = row < NN ? row : NN - 1;
    const int lq = l >> 4;
    f32x4 acc[8];
#pragma unroll
    for (int c = 0; c < 8; ++c) acc[c] = (f32x4){0.f, 0.f, 0.f, 0.f};
#pragma unroll
    for (int tt = 0; tt < 4; ++tt) {
        const float4* xp = (const float4*)(X + (size_t)rc * 128 + tt * 32 + lq * 8);
        float4 xa = xp[0], xb = xp[1];
        bf16x8 xf;
        unsigned* xu = (unsigned*)&xf;
        xu[0] = pack_bf16x2(xa.x, xa.y);
        xu[1] = pack_bf16x2(xa.z, xa.w);
        xu[2] = pack_bf16x2(xb.x, xb.y);
        xu[3] = pack_bf16x2(xb.z, xb.w);
#pragma unroll
        for (int c = 0; c < 8; ++c) {
            bf16x8 wf = *(const bf16x8*)(Wpk + (size_t)((c * 4 + tt) * 64 + l) * 8);
            acc[c] = __builtin_amdgcn_mfma_f32_16x16x32_bf16(wf, xf, acc[c], 0, 0, 0);
        }
    }
    if (row < NN) {
        float s = dinv[row];
        uint2* orow = (uint2*)(Hb + (size_t)row * 64);
#pragma unroll
        for (int c = 0; c < 8; ++c) {
            uint2 p;
            p.x = pack_bf16x2(acc[c][0] * s, acc[c][1] * s);
            p.y = pack_bf16x2(acc[c][2] * s, acc[c][3] * s);
            orow[c * 4 + lq] = p;
        }
    }
}

// ---------------- MFMA GEMM2: Hb2[N,32 u32] = pack_bf16(dinv * (X2 @ W2)) ----------------
__global__ __launch_bounds__(256) void k_gemm2(const unsigned short* __restrict__ Xb,
                                               const unsigned short* __restrict__ Wpk,
                                               const float* __restrict__ dinv,
                                               unsigned* __restrict__ Hb) {
    const int t = threadIdx.x;
    const int w = t >> 6, l = t & 63;
    const int row = blockIdx.x * 64 + w * 16 + (l & 15);
    const int rc = row < NN ? row : NN - 1;
    const int lq = l >> 4;
    f32x4 acc[4];
#pragma unroll
    for (int c = 0; c < 4; ++c) acc[c] = (f32x4){0.f, 0.f, 0.f, 0.f};
#pragma unroll
    for (int tt = 0; tt < 4; ++tt) {
        bf16x8 xf = *(const bf16x8*)(Xb + (size_t)rc * 128 + tt * 32 + lq * 8);
#pragma unroll
        for (int c = 0; c < 4; ++c) {
            bf16x8 wf = *(const bf16x8*)(Wpk + (size_t)((c * 4 + tt) * 64 + l) * 8);
            acc[c] = __builtin_amdgcn_mfma_f32_16x16x32_bf16(wf, xf, acc[c], 0, 0, 0);
        }
    }
    if (row < NN) {
        float s = dinv[row];
        uint2* orow = (uint2*)(Hb + (size_t)row * 32);
#pragma unroll
        for (int c = 0; c < 4; ++c) {
            uint2 p;
            p.x = pack_bf16x2(acc[c][0] * s, acc[c][1] * s);
            p.y = pack_bf16x2(acc[c][2] * s, acc[c][3] * s);
            orow[c * 4 + lq] = p;
        }
    }
}

// ---------------- layer-1 aggregate: quarter-wave, uint4/lane = full 256B row per load ----------------
__global__ void k_agg1(const int* __restrict__ row_start, const unsigned short* __restrict__ esrc,
                       const unsigned* __restrict__ Hb, const float* __restrict__ dinv,
                       const float* __restrict__ b, unsigned* __restrict__ X2b) {
    int wid = (blockIdx.x * blockDim.x + threadIdx.x) >> 6;
    int lane = threadIdx.x & 63;
    if (wid >= NN) return;
    int beg = row_start[wid];
    int n = row_start[wid + 1] - beg;
    int q = lane >> 4, l16 = lane & 15;
    int qb = beg + ((n * q) >> 2);
    int qe = beg + ((n * (q + 1)) >> 2);
    const uint4* Hp = (const uint4*)Hb;  // row = 16 uint4
    float a0 = 0.f, a1 = 0.f, a2 = 0.f, a3 = 0.f, a4 = 0.f, a5 = 0.f, a6 = 0.f, a7 = 0.f;
    int j = qb;
    for (; j + 4 <= qe; j += 4) {
        int s0 = esrc[j], s1 = esrc[j + 1], s2 = esrc[j + 2], s3 = esrc[j + 3];
        uint4 v0 = Hp[(size_t)s0 * 16 + l16];
        uint4 v1 = Hp[(size_t)s1 * 16 + l16];
        uint4 v2 = Hp[(size_t)s2 * 16 + l16];
        uint4 v3 = Hp[(size_t)s3 * 16 + l16];
        a0 += bf16_lo(v0.x) + bf16_lo(v1.x) + bf16_lo(v2.x) + bf16_lo(v3.x);
        a1 += bf16_hi(v0.x) + bf16_hi(v1.x) + bf16_hi(v2.x) + bf16_hi(v3.x);
        a2 += bf16_lo(v0.y) + bf16_lo(v1.y) + bf16_lo(v2.y) + bf16_lo(v3.y);
        a3 += bf16_hi(v0.y) + bf16_hi(v1.y) + bf16_hi(v2.y) + bf16_hi(v3.y);
        a4 += bf16_lo(v0.z) + bf16_lo(v1.z) + bf16_lo(v2.z) + bf16_lo(v3.z);
        a5 += bf16_hi(v0.z) + bf16_hi(v1.z) + bf16_hi(v2.z) + bf16_hi(v3.z);
        a6 += bf16_lo(v0.w) + bf16_lo(v1.w) + bf16_lo(v2.w) + bf16_lo(v3.w);
        a7 += bf16_hi(v0.w) + bf16_hi(v1.w) + bf16_hi(v2.w) + bf16_hi(v3.w);
    }
    for (; j < qe; ++j) {
        uint4 v = Hp[(size_t)esrc[j] * 16 + l16];
        a0 += bf16_lo(v.x); a1 += bf16_hi(v.x);
        a2 += bf16_lo(v.y); a3 += bf16_hi(v.y);
        a4 += bf16_lo(v.z); a5 += bf16_hi(v.z);
        a6 += bf16_lo(v.w); a7 += bf16_hi(v.w);
    }
    if (q == 0) {  // self-loop, counted once
        uint4 v = Hp[(size_t)wid * 16 + l16];
        a0 += bf16_lo(v.x); a1 += bf16_hi(v.x);
        a2 += bf16_lo(v.y); a3 += bf16_hi(v.y);
        a4 += bf16_lo(v.z); a5 += bf16_hi(v.z);
        a6 += bf16_lo(v.w); a7 += bf16_hi(v.w);
    }
    a0 += __shfl_xor(a0, 16); a0 += __shfl_xor(a0, 32);
    a1 += __shfl_xor(a1, 16); a1 += __shfl_xor(a1, 32);
    a2 += __shfl_xor(a2, 16); a2 += __shfl_xor(a2, 32);
    a3 += __shfl_xor(a3, 16); a3 += __shfl_xor(a3, 32);
    a4 += __shfl_xor(a4, 16); a4 += __shfl_xor(a4, 32);
    a5 += __shfl_xor(a5, 16); a5 += __shfl_xor(a5, 32);
    a6 += __shfl_xor(a6, 16); a6 += __shfl_xor(a6, 32);
    a7 += __shfl_xor(a7, 16); a7 += __shfl_xor(a7, 32);
    if (q == 0) {
        float di = dinv[wid];
        float4 b0 = ((const float4*)b)[l16 * 2];
        float4 b1 = ((const float4*)b)[l16 * 2 + 1];
        uint4 st;
        st.x = pack_bf16x2(fmaxf(fmaf(di, a0, b0.x), 0.f), fmaxf(fmaf(di, a1, b0.y), 0.f));
        st.y = pack_bf16x2(fmaxf(fmaf(di, a2, b0.z), 0.f), fmaxf(fmaf(di, a3, b0.w), 0.f));
        st.z = pack_bf16x2(fmaxf(fmaf(di, a4, b1.x), 0.f), fmaxf(fmaf(di, a5, b1.y), 0.f));
        st.w = pack_bf16x2(fmaxf(fmaf(di, a6, b1.z), 0.f), fmaxf(fmaf(di, a7, b1.w), 0.f));
        ((uint4*)X2b)[(size_t)wid * 16 + l16] = st;
    }
}

// ---------------- layer-2 aggregate + log_softmax: quarter-wave, uint2/lane = 128B row/load ----------------
__global__ void k_agg2_lsm(const int* __restrict__ row_start, const unsigned short* __restrict__ esrc,
                           const unsigned* __restrict__ Hb, const float* __restrict__ dinv,
                           const float* __restrict__ b, float* __restrict__ OUT) {
    int wid = (blockIdx.x * blockDim.x + threadIdx.x) >> 6;
    int lane = threadIdx.x & 63;
    if (wid >= NN) return;
    int beg = row_start[wid];
    int n = row_start[wid + 1] - beg;
    int q = lane >> 4, l16 = lane & 15;
    int qb = beg + ((n * q) >> 2);
    int qe = beg + ((n * (q + 1)) >> 2);
    const uint2* Hp = (const uint2*)Hb;  // row = 16 uint2
    float a0 = 0.f, a1 = 0.f, a2 = 0.f, a3 = 0.f;
    int j = qb;
    for (; j + 4 <= qe; j += 4) {
        int s0 = esrc[j], s1 = esrc[j + 1], s2 = esrc[j + 2], s3 = esrc[j + 3];
        uint2 v0 = Hp[(size_t)s0 * 16 + l16];
        uint2 v1 = Hp[(size_t)s1 * 16 + l16];
        uint2 v2 = Hp[(size_t)s2 * 16 + l16];
        uint2 v3 = Hp[(size_t)s3 * 16 + l16];
        a0 += bf16_lo(v0.x) + bf16_lo(v1.x) + bf16_lo(v2.x) + bf16_lo(v3.x);
        a1 += bf16_hi(v0.x) + bf16_hi(v1.x) + bf16_hi(v2.x) + bf16_hi(v3.x);
        a2 += bf16_lo(v0.y) + bf16_lo(v1.y) + bf16_lo(v2.y) + bf16_lo(v3.y);
        a3 += bf16_hi(v0.y) + bf16_hi(v1.y) + bf16_hi(v2.y) + bf16_hi(v3.y);
    }
    for (; j < qe; ++j) {
        uint2 v = Hp[(size_t)esrc[j] * 16 + l16];
        a0 += bf16_lo(v.x); a1 += bf16_hi(v.x);
        a2 += bf16_lo(v.y); a3 += bf16_hi(v.y);
    }
    if (q == 0) {  // self-loop
        uint2 v = Hp[(size_t)wid * 16 + l16];
        a0 += bf16_lo(v.x); a1 += bf16_hi(v.x);
        a2 += bf16_lo(v.y); a3 += bf16_hi(v.y);
    }
    a0 += __shfl_xor(a0, 16); a0 += __shfl_xor(a0, 32);
    a1 += __shfl_xor(a1, 16); a1 += __shfl_xor(a1, 32);
    a2 += __shfl_xor(a2, 16); a2 += __shfl_xor(a2, 32);
    a3 += __shfl_xor(a3, 16); a3 += __shfl_xor(a3, 32);
    float di = dinv[wid];
    float4 bv = ((const float4*)b)[l16];
    float v0 = fmaf(di, a0, bv.x);
    float v1 = fmaf(di, a1, bv.y);
    float v2 = fmaf(di, a2, bv.z);
    float v3 = fmaf(di, a3, bv.w);
    float m = fmaxf(fmaxf(v0, v1), fmaxf(v2, v3));
#pragma unroll
    for (int o = 8; o > 0; o >>= 1) m = fmaxf(m, __shfl_xor(m, o));
    float s = expf(v0 - m) + expf(v1 - m) + expf(v2 - m) + expf(v3 - m);
#pragma unroll
    for (int o = 8; o > 0; o >>= 1) s += __shfl_xor(s, o);
    float ls = m + logf(s);
    if (q == 0) {
        float4 o4;
        o4.x = v0 - ls;
        o4.y = v1 - ls;
        o4.z = v2 - ls;
        o4.w = v3 - ls;
        ((float4*)OUT)[(size_t)wid * 16 + l16] = o4;
    }
}

extern "C" void kernel_launch(void* const* d_in, const int* in_sizes, int n_in,
                              void* d_out, int out_size, void* d_ws, size_t ws_size,
                              hipStream_t stream) {
    const float* x = (const float*)d_in[0];
    const int* ei = (const int*)d_in[1];  // [2, NE] int32
    const float* W1 = (const float*)d_in[2];
    const float* b1 = (const float*)d_in[3];
    const float* W2 = (const float*)d_in[4];
    const float* b2 = (const float*)d_in[5];
    float* out = (float*)d_out;

    const int* src = ei;
    const int* dst = ei + NE;

    // workspace layout (all segments 16B-aligned)
    int* bbase = (int*)d_ws;                                 // 400
    int* pbh = bbase + 400;                                  // NCH*NBP
    unsigned* eord = (unsigned*)(pbh + NCH * NBP);           // NE
    unsigned short* esrc16 = (unsigned short*)(eord + NE);   // NE
    int* row_start = (int*)(esrc16 + NE);                    // 50016
    float* dinv = (float*)(row_start + 50016);               // NN
    unsigned short* Wpk1 = (unsigned short*)(dinv + NN);     // 2048*8 bf16 (32KB)
    unsigned short* Wpk2 = Wpk1 + 2048 * 8;                  // 1024*8 bf16 (16KB)
    unsigned* H1b = (unsigned*)(Wpk2 + 1024 * 8);            // NN*64 u32
    unsigned* H2b = H1b + (size_t)NN * 64;                   // NN*32 u32
    unsigned* X2b = H2b + (size_t)NN * 32;                   // NN*64 u32 (bf16x2)

    k_wpack<<<12, 256, 0, stream>>>(W1, W2, Wpk1, Wpk2);
    k_hist<<<NCH, 256, 0, stream>>>(dst, pbh);
    k_bscan<<<1, 512, 0, stream>>>(pbh, bbase);
    k_scat1<<<NCH, 256, 0, stream>>>(src, dst, pbh, eord);
    k_scat2<<<NB, 256, 0, stream>>>(bbase, eord, esrc16, row_start, dinv);

    // layer 1
    k_gemm1<<<(NN + 63) / 64, 256, 0, stream>>>(x, Wpk1, dinv, H1b);
    k_agg1<<<(NN * 64 + 255) / 256, 256, 0, stream>>>(row_start, esrc16, H1b, dinv, b1, X2b);
    // layer 2
    k_gemm2<<<(NN + 63) / 64, 256, 0, stream>>>((const unsigned short*)X2b, Wpk2, dinv, H2b);
    k_agg2_lsm<<<(NN * 64 + 255) / 256, 256, 0, stream>>>(row_start, esrc16, H2b, dinv, b2, out);
}

// Round 10
// 123.463 us; speedup vs baseline: 17.3488x; 1.1481x over previous
//
#include <hip/hip_runtime.h>

#define NN 50000
#define NE 800000
#define NB 391            // dst buckets of 128 nodes (391*128 = 50048)
#define NBP 392           // padded row stride for pbh
#define CHUNK 8192        // edges per pass-1 block
#define NCH ((NE + CHUNK - 1) / CHUNK)  // 98 blocks

typedef __attribute__((ext_vector_type(8))) short bf16x8;
typedef __attribute__((ext_vector_type(4))) float f32x4;
typedef __attribute__((ext_vector_type(2))) float f32x2;

__device__ __forceinline__ unsigned pack_bf16x2(float a, float b) {
    unsigned ua = __float_as_uint(a);
    unsigned ub = __float_as_uint(b);
    ua = (ua + 0x7FFFu + ((ua >> 16) & 1u)) >> 16;
    ub = (ub + 0x7FFFu + ((ub >> 16) & 1u)) >> 16;
    return ua | (ub << 16);
}
// pack 4 floats -> 4 fp8 e4m3 (one u32)
__device__ __forceinline__ unsigned pack_fp8x4(float a, float b, float c, float d) {
    int w = __builtin_amdgcn_cvt_pk_fp8_f32(a, b, 0, false);
    w = __builtin_amdgcn_cvt_pk_fp8_f32(c, d, w, true);
    return (unsigned)w;
}

// ---------------- fused prep: bucket histogram (blocks 0..NCH-1) + W pack (blocks NCH..) ----------------
__global__ void k_hist(const int* __restrict__ dst, int* __restrict__ pbh,
                       const float* __restrict__ W1, const float* __restrict__ W2,
                       unsigned short* __restrict__ Wpk1, unsigned short* __restrict__ Wpk2) {
    const int t = threadIdx.x;
    if (blockIdx.x >= NCH) {  // W-pack part
        int gid = (blockIdx.x - NCH) * 256 + t;
        const float* W;
        unsigned short* Wpk;
        int idx, M;
        if (gid < 2048) { W = W1; Wpk = Wpk1; idx = gid; M = 128; }
        else if (gid < 3072) { W = W2; Wpk = Wpk2; idx = gid - 2048; M = 64; }
        else return;
        int l = idx & 63;
        int tt = (idx >> 6) & 3;
        int ct = idx >> 8;
        int col = ct * 16 + (l & 15);
        int k0 = tt * 32 + (l >> 4) * 8;
        unsigned* o = (unsigned*)(Wpk + (size_t)idx * 8);
#pragma unroll
        for (int j = 0; j < 8; j += 2)
            o[j >> 1] = pack_bf16x2(W[(size_t)(k0 + j) * M + col], W[(size_t)(k0 + j + 1) * M + col]);
        return;
    }
    __shared__ int h[NB];
    for (int j = t; j < NB; j += 256) h[j] = 0;
    __syncthreads();
    const int e0 = blockIdx.x * CHUNK;
#pragma unroll 8
    for (int i = 0; i < 32; ++i) {
        int e = e0 + t + i * 256;
        if (e < NE) atomicAdd(&h[dst[e] >> 7], 1);
    }
    __syncthreads();
    for (int j = t; j < NB; j += 256) pbh[blockIdx.x * NBP + j] = h[j];
}

// ---------------- bucket totals + exclusive scan + per-chunk bases ----------------
__global__ void k_bscan(int* __restrict__ pbh, int* __restrict__ bbase) {
    __shared__ int s[512];
    const int t = threadIdx.x;
    int tot = 0;
    if (t < NB)
        for (int c = 0; c < NCH; ++c) tot += pbh[c * NBP + t];
    s[t] = (t < NB) ? tot : 0;
    __syncthreads();
    for (int o = 1; o < 512; o <<= 1) {
        int a = (t >= o) ? s[t - o] : 0;
        __syncthreads();
        s[t] += a;
        __syncthreads();
    }
    int ex = s[t] - tot;
    if (t < NB) {
        bbase[t] = ex;
        int run = ex;
        for (int c = 0; c < NCH; ++c) {
            int tmp = pbh[c * NBP + t];
            pbh[c * NBP + t] = run;
            run += tmp;
        }
    }
    if (t == 0) bbase[NB] = NE;
}

// ---------------- pass 1: bucket-bin edges ----------------
__global__ void k_scat1(const int* __restrict__ src, const int* __restrict__ dst,
                        const int* __restrict__ pbh, unsigned* __restrict__ eord) {
    __shared__ int cur[NB];
    const int t = threadIdx.x;
    const int e0 = blockIdx.x * CHUNK;
    for (int j = t; j < NB; j += 256) cur[j] = pbh[blockIdx.x * NBP + j];
    __syncthreads();
#pragma unroll 8
    for (int i = 0; i < 32; ++i) {
        int e = e0 + t + i * 256;
        if (e < NE) {
            unsigned s = (unsigned)src[e];
            unsigned d = (unsigned)dst[e];
            int pos = atomicAdd(&cur[d >> 7], 1);
            eord[pos] = ((d & 127u) << 16) | s;
        }
    }
}

// ---------------- pass 2: within-bucket sort + row_start + dinv ----------------
__global__ void k_scat2(const int* __restrict__ bbase, const unsigned* __restrict__ eord,
                        unsigned short* __restrict__ esrc16, int* __restrict__ row_start,
                        float* __restrict__ dinv) {
    __shared__ int cnt[128];
    __shared__ int pre[128];
    __shared__ int cur[128];
    const int b = blockIdx.x, t = threadIdx.x, d0 = b << 7;
    if (t < 128) cnt[t] = 0;
    __syncthreads();
    const int beg = bbase[b], end = bbase[b + 1];
    for (int i = beg + t; i < end; i += 256) atomicAdd(&cnt[(eord[i] >> 16) & 127], 1);
    __syncthreads();
    int v = (t < 128) ? cnt[t] : 0;
    if (t < 128) pre[t] = v;
    __syncthreads();
    for (int o = 1; o < 128; o <<= 1) {
        int a = (t < 128 && t >= o) ? pre[t - o] : 0;
        __syncthreads();
        if (t < 128) pre[t] += a;
        __syncthreads();
    }
    if (t < 128) {
        int ex = beg + pre[t] - v;
        int d = d0 + t;
        if (d < NN) {
            row_start[d] = ex;
            dinv[d] = rsqrtf((float)(v + 1));  // +1 self-loop
        }
        cur[t] = ex;
    }
    if (b == NB - 1 && t == 0) row_start[NN] = NE;
    __syncthreads();
    for (int i = beg + t; i < end; i += 256) {
        unsigned x = eord[i];
        int pos = atomicAdd(&cur[(x >> 16) & 127], 1);
        esrc16[pos] = (unsigned short)(x & 0xFFFFu);
    }
}

// ---------------- MFMA GEMM1: H1f8[N,32 u32] = fp8(dinv * (X @ W1)), reads f32 X ----------------
// 4 waves/block, wave = 16 rows. lane l: row r0+(l&15), cols c*16 + lq*4 + q.
__global__ __launch_bounds__(256) void k_gemm1(const float* __restrict__ X,
                                               const unsigned short* __restrict__ Wpk,
                                               const float* __restrict__ dinv,
                                               unsigned* __restrict__ H1) {
    const int t = threadIdx.x;
    const int w = t >> 6, l = t & 63;
    const int row = blockIdx.x * 64 + w * 16 + (l & 15);
    const int rc = row < NN ? row : NN - 1;
    const int lq = l >> 4;
    f32x4 acc[8];
#pragma unroll
    for (int c = 0; c < 8; ++c) acc[c] = (f32x4){0.f, 0.f, 0.f, 0.f};
#pragma unroll
    for (int tt = 0; tt < 4; ++tt) {
        const float4* xp = (const float4*)(X + (size_t)rc * 128 + tt * 32 + lq * 8);
        float4 xa = xp[0], xb = xp[1];
        bf16x8 xf;
        unsigned* xu = (unsigned*)&xf;
        xu[0] = pack_bf16x2(xa.x, xa.y);
        xu[1] = pack_bf16x2(xa.z, xa.w);
        xu[2] = pack_bf16x2(xb.x, xb.y);
        xu[3] = pack_bf16x2(xb.z, xb.w);
#pragma unroll
        for (int c = 0; c < 8; ++c) {
            bf16x8 wf = *(const bf16x8*)(Wpk + (size_t)((c * 4 + tt) * 64 + l) * 8);
            acc[c] = __builtin_amdgcn_mfma_f32_16x16x32_bf16(wf, xf, acc[c], 0, 0, 0);
        }
    }
    if (row < NN) {
        float s = dinv[row];
        unsigned* orow = H1 + (size_t)row * 32;
#pragma unroll
        for (int c = 0; c < 8; ++c)
            orow[c * 4 + lq] = pack_fp8x4(acc[c][0] * s, acc[c][1] * s, acc[c][2] * s, acc[c][3] * s);
    }
}

// ---------------- MFMA GEMM2: H2f8[N,16 u32] = fp8(dinv * (X2 @ W2)) ----------------
__global__ __launch_bounds__(256) void k_gemm2(const unsigned short* __restrict__ Xb,
                                               const unsigned short* __restrict__ Wpk,
                                               const float* __restrict__ dinv,
                                               unsigned* __restrict__ H2) {
    const int t = threadIdx.x;
    const int w = t >> 6, l = t & 63;
    const int row = blockIdx.x * 64 + w * 16 + (l & 15);
    const int rc = row < NN ? row : NN - 1;
    const int lq = l >> 4;
    f32x4 acc[4];
#pragma unroll
    for (int c = 0; c < 4; ++c) acc[c] = (f32x4){0.f, 0.f, 0.f, 0.f};
#pragma unroll
    for (int tt = 0; tt < 4; ++tt) {
        bf16x8 xf = *(const bf16x8*)(Xb + (size_t)rc * 128 + tt * 32 + lq * 8);
#pragma unroll
        for (int c = 0; c < 4; ++c) {
            bf16x8 wf = *(const bf16x8*)(Wpk + (size_t)((c * 4 + tt) * 64 + l) * 8);
            acc[c] = __builtin_amdgcn_mfma_f32_16x16x32_bf16(wf, xf, acc[c], 0, 0, 0);
        }
    }
    if (row < NN) {
        float s = dinv[row];
        unsigned* orow = H2 + (size_t)row * 16;
#pragma unroll
        for (int c = 0; c < 4; ++c)
            orow[c * 4 + lq] = pack_fp8x4(acc[c][0] * s, acc[c][1] * s, acc[c][2] * s, acc[c][3] * s);
    }
}

// ---------------- layer-1 aggregate: quarter-wave, uint2/lane = full 128B fp8 row per load ----------------
__global__ void k_agg1(const int* __restrict__ row_start, const unsigned short* __restrict__ esrc,
                       const unsigned* __restrict__ H1, const float* __restrict__ dinv,
                       const float* __restrict__ b, unsigned* __restrict__ X2b) {
    int wid = (blockIdx.x * blockDim.x + threadIdx.x) >> 6;
    int lane = threadIdx.x & 63;
    if (wid >= NN) return;
    int beg = row_start[wid];
    int n = row_start[wid + 1] - beg;
    int q = lane >> 4, l16 = lane & 15;
    int qb = beg + ((n * q) >> 2);
    int qe = beg + ((n * (q + 1)) >> 2);
    const uint2* Hp = (const uint2*)H1;  // row = 16 uint2
    float a0 = 0.f, a1 = 0.f, a2 = 0.f, a3 = 0.f, a4 = 0.f, a5 = 0.f, a6 = 0.f, a7 = 0.f;
    int j = qb;
    for (; j + 4 <= qe; j += 4) {
        int s0 = esrc[j], s1 = esrc[j + 1], s2 = esrc[j + 2], s3 = esrc[j + 3];
        uint2 v0 = Hp[(size_t)s0 * 16 + l16];
        uint2 v1 = Hp[(size_t)s1 * 16 + l16];
        uint2 v2 = Hp[(size_t)s2 * 16 + l16];
        uint2 v3 = Hp[(size_t)s3 * 16 + l16];
#pragma unroll
        for (int k = 0; k < 4; ++k) {
            unsigned lo = (k == 0) ? v0.x : (k == 1) ? v1.x : (k == 2) ? v2.x : v3.x;
            unsigned hi = (k == 0) ? v0.y : (k == 1) ? v1.y : (k == 2) ? v2.y : v3.y;
            f32x2 p0 = __builtin_amdgcn_cvt_pk_f32_fp8(lo, false);
            f32x2 p1 = __builtin_amdgcn_cvt_pk_f32_fp8(lo, true);
            f32x2 p2 = __builtin_amdgcn_cvt_pk_f32_fp8(hi, false);
            f32x2 p3 = __builtin_amdgcn_cvt_pk_f32_fp8(hi, true);
            a0 += p0.x; a1 += p0.y; a2 += p1.x; a3 += p1.y;
            a4 += p2.x; a5 += p2.y; a6 += p3.x; a7 += p3.y;
        }
    }
    for (; j < qe; ++j) {
        uint2 v = Hp[(size_t)esrc[j] * 16 + l16];
        f32x2 p0 = __builtin_amdgcn_cvt_pk_f32_fp8(v.x, false);
        f32x2 p1 = __builtin_amdgcn_cvt_pk_f32_fp8(v.x, true);
        f32x2 p2 = __builtin_amdgcn_cvt_pk_f32_fp8(v.y, false);
        f32x2 p3 = __builtin_amdgcn_cvt_pk_f32_fp8(v.y, true);
        a0 += p0.x; a1 += p0.y; a2 += p1.x; a3 += p1.y;
        a4 += p2.x; a5 += p2.y; a6 += p3.x; a7 += p3.y;
    }
    if (q == 0) {  // self-loop, counted once
        uint2 v = Hp[(size_t)wid * 16 + l16];
        f32x2 p0 = __builtin_amdgcn_cvt_pk_f32_fp8(v.x, false);
        f32x2 p1 = __builtin_amdgcn_cvt_pk_f32_fp8(v.x, true);
        f32x2 p2 = __builtin_amdgcn_cvt_pk_f32_fp8(v.y, false);
        f32x2 p3 = __builtin_amdgcn_cvt_pk_f32_fp8(v.y, true);
        a0 += p0.x; a1 += p0.y; a2 += p1.x; a3 += p1.y;
        a4 += p2.x; a5 += p2.y; a6 += p3.x; a7 += p3.y;
    }
    a0 += __shfl_xor(a0, 16); a0 += __shfl_xor(a0, 32);
    a1 += __shfl_xor(a1, 16); a1 += __shfl_xor(a1, 32);
    a2 += __shfl_xor(a2, 16); a2 += __shfl_xor(a2, 32);
    a3 += __shfl_xor(a3, 16); a3 += __shfl_xor(a3, 32);
    a4 += __shfl_xor(a4, 16); a4 += __shfl_xor(a4, 32);
    a5 += __shfl_xor(a5, 16); a5 += __shfl_xor(a5, 32);
    a6 += __shfl_xor(a6, 16); a6 += __shfl_xor(a6, 32);
    a7 += __shfl_xor(a7, 16); a7 += __shfl_xor(a7, 32);
    if (q == 0) {
        float di = dinv[wid];
        float4 b0 = ((const float4*)b)[l16 * 2];
        float4 b1 = ((const float4*)b)[l16 * 2 + 1];
        uint4 st;
        st.x = pack_bf16x2(fmaxf(fmaf(di, a0, b0.x), 0.f), fmaxf(fmaf(di, a1, b0.y), 0.f));
        st.y = pack_bf16x2(fmaxf(fmaf(di, a2, b0.z), 0.f), fmaxf(fmaf(di, a3, b0.w), 0.f));
        st.z = pack_bf16x2(fmaxf(fmaf(di, a4, b1.x), 0.f), fmaxf(fmaf(di, a5, b1.y), 0.f));
        st.w = pack_bf16x2(fmaxf(fmaf(di, a6, b1.z), 0.f), fmaxf(fmaf(di, a7, b1.w), 0.f));
        ((uint4*)X2b)[(size_t)wid * 16 + l16] = st;
    }
}

// ---------------- layer-2 aggregate + log_softmax: quarter-wave, u32/lane = 64B fp8 row/load ----------------
__global__ void k_agg2_lsm(const int* __restrict__ row_start, const unsigned short* __restrict__ esrc,
                           const unsigned* __restrict__ H2, const float* __restrict__ dinv,
                           const float* __restrict__ b, float* __restrict__ OUT) {
    int wid = (blockIdx.x * blockDim.x + threadIdx.x) >> 6;
    int lane = threadIdx.x & 63;
    if (wid >= NN) return;
    int beg = row_start[wid];
    int n = row_start[wid + 1] - beg;
    int q = lane >> 4, l16 = lane & 15;
    int qb = beg + ((n * q) >> 2);
    int qe = beg + ((n * (q + 1)) >> 2);
    float a0 = 0.f, a1 = 0.f, a2 = 0.f, a3 = 0.f;
    int j = qb;
    for (; j + 4 <= qe; j += 4) {
        int s0 = esrc[j], s1 = esrc[j + 1], s2 = esrc[j + 2], s3 = esrc[j + 3];
        unsigned v0 = H2[(size_t)s0 * 16 + l16];
        unsigned v1 = H2[(size_t)s1 * 16 + l16];
        unsigned v2 = H2[(size_t)s2 * 16 + l16];
        unsigned v3 = H2[(size_t)s3 * 16 + l16];
#pragma unroll
        for (int k = 0; k < 4; ++k) {
            unsigned v = (k == 0) ? v0 : (k == 1) ? v1 : (k == 2) ? v2 : v3;
            f32x2 p0 = __builtin_amdgcn_cvt_pk_f32_fp8(v, false);
            f32x2 p1 = __builtin_amdgcn_cvt_pk_f32_fp8(v, true);
            a0 += p0.x; a1 += p0.y; a2 += p1.x; a3 += p1.y;
        }
    }
    for (; j < qe; ++j) {
        unsigned v = H2[(size_t)esrc[j] * 16 + l16];
        f32x2 p0 = __builtin_amdgcn_cvt_pk_f32_fp8(v, false);
        f32x2 p1 = __builtin_amdgcn_cvt_pk_f32_fp8(v, true);
        a0 += p0.x; a1 += p0.y; a2 += p1.x; a3 += p1.y;
    }
    if (q == 0) {  // self-loop
        unsigned v = H2[(size_t)wid * 16 + l16];
        f32x2 p0 = __builtin_amdgcn_cvt_pk_f32_fp8(v, false);
        f32x2 p1 = __builtin_amdgcn_cvt_pk_f32_fp8(v, true);
        a0 += p0.x; a1 += p0.y; a2 += p1.x; a3 += p1.y;
    }
    a0 += __shfl_xor(a0, 16); a0 += __shfl_xor(a0, 32);
    a1 += __shfl_xor(a1, 16); a1 += __shfl_xor(a1, 32);
    a2 += __shfl_xor(a2, 16); a2 += __shfl_xor(a2, 32);
    a3 += __shfl_xor(a3, 16); a3 += __shfl_xor(a3, 32);
    float di = dinv[wid];
    float4 bv = ((const float4*)b)[l16];
    float v0 = fmaf(di, a0, bv.x);
    float v1 = fmaf(di, a1, bv.y);
    float v2 = fmaf(di, a2, bv.z);
    float v3 = fmaf(di, a3, bv.w);
    float m = fmaxf(fmaxf(v0, v1), fmaxf(v2, v3));
#pragma unroll
    for (int o = 8; o > 0; o >>= 1) m = fmaxf(m, __shfl_xor(m, o));
    float s = expf(v0 - m) + expf(v1 - m) + expf(v2 - m) + expf(v3 - m);
#pragma unroll
    for (int o = 8; o > 0; o >>= 1) s += __shfl_xor(s, o);
    float ls = m + logf(s);
    if (q == 0) {
        float4 o4;
        o4.x = v0 - ls;
        o4.y = v1 - ls;
        o4.z = v2 - ls;
        o4.w = v3 - ls;
        ((float4*)OUT)[(size_t)wid * 16 + l16] = o4;
    }
}

extern "C" void kernel_launch(void* const* d_in, const int* in_sizes, int n_in,
                              void* d_out, int out_size, void* d_ws, size_t ws_size,
                              hipStream_t stream) {
    const float* x = (const float*)d_in[0];
    const int* ei = (const int*)d_in[1];  // [2, NE] int32
    const float* W1 = (const float*)d_in[2];
    const float* b1 = (const float*)d_in[3];
    const float* W2 = (const float*)d_in[4];
    const float* b2 = (const float*)d_in[5];
    float* out = (float*)d_out;

    const int* src = ei;
    const int* dst = ei + NE;

    // workspace layout (all segments 16B-aligned)
    int* bbase = (int*)d_ws;                                 // 400
    int* pbh = bbase + 400;                                  // NCH*NBP
    unsigned* eord = (unsigned*)(pbh + NCH * NBP);           // NE
    unsigned short* esrc16 = (unsigned short*)(eord + NE);   // NE
    int* row_start = (int*)(esrc16 + NE);                    // 50016
    float* dinv = (float*)(row_start + 50016);               // NN
    unsigned short* Wpk1 = (unsigned short*)(dinv + NN);     // 2048*8 bf16 (32KB)
    unsigned short* Wpk2 = Wpk1 + 2048 * 8;                  // 1024*8 bf16 (16KB)
    unsigned* H1f8 = (unsigned*)(Wpk2 + 1024 * 8);           // NN*32 u32 (fp8x4, 6.4MB)
    unsigned* H2f8 = H1f8 + (size_t)NN * 32;                 // NN*16 u32 (fp8x4, 3.2MB)
    unsigned* X2b = H2f8 + (size_t)NN * 16;                  // NN*64 u32 (bf16x2)

    k_hist<<<NCH + 12, 256, 0, stream>>>(dst, pbh, W1, W2, Wpk1, Wpk2);
    k_bscan<<<1, 512, 0, stream>>>(pbh, bbase);
    k_scat1<<<NCH, 256, 0, stream>>>(src, dst, pbh, eord);
    k_scat2<<<NB, 256, 0, stream>>>(bbase, eord, esrc16, row_start, dinv);

    // layer 1
    k_gemm1<<<(NN + 63) / 64, 256, 0, stream>>>(x, Wpk1, dinv, H1f8);
    k_agg1<<<(NN * 64 + 255) / 256, 256, 0, stream>>>(row_start, esrc16, H1f8, dinv, b1, X2b);
    // layer 2
    k_gemm2<<<(NN + 63) / 64, 256, 0, stream>>>((const unsigned short*)X2b, Wpk2, dinv, H2f8);
    k_agg2_lsm<<<(NN * 64 + 255) / 256, 256, 0, stream>>>(row_start, esrc16, H2f8, dinv, b2, out);
}